// Round 10
// baseline (188.825 us; speedup 1.0000x reference)
//
#include <hip/hip_runtime.h>
#include <hip/hip_bf16.h>

// ---------------------------------------------------------------------------
// MultiHeadAttention for MI355X (gfx950)
// B=8 S=4096 Q=32 H=8 D=64 IN=512 NKV=1024
// R14: k_gemm2 REVERTED to R12 single-buffered form (R13's dbuf cost
//      occupancy 23->17% and regressed). k_attn: denL removed (den partials
//      via atomicAdd on memset-zeroed den_part) -> LDS exactly 80 KiB ->
//      2 blocks/CU; grid split (32,8,2) so 2 co-resident blocks/CU overlap
//      staging with compute. Everything else unchanged from R12.
// Fallback: R1-verified 3-kernel path if ws_size < 120 MB.
// ---------------------------------------------------------------------------

typedef float f32x4 __attribute__((ext_vector_type(4)));
typedef short s16x8 __attribute__((ext_vector_type(8)));

__device__ __forceinline__ unsigned short f2bf(float f) {
  union { __hip_bfloat16 h; unsigned short u; } cv;
  cv.h = __float2bfloat16(f);
  return cv.u;
}
__device__ __forceinline__ float bf2f(unsigned short u) {
  union { unsigned short u; __hip_bfloat16 h; } cv;
  cv.u = u;
  return __bfloat162float(cv.h);
}
__device__ __forceinline__ float tofl(float v) { return v; }
__device__ __forceinline__ float tofl(__hip_bfloat16 v) { return __bfloat162float(v); }

__device__ __forceinline__ f32x4 mfma16(s16x8 a, s16x8 b, f32x4 c) {
  return __builtin_amdgcn_mfma_f32_16x16x32_bf16(a, b, c, 0, 0, 0);
}

// dtype detection (1 = fp32, 0 = bf16)
__device__ __forceinline__ int detect_fp32(const unsigned short* __restrict__ in16) {
  unsigned short v = in16[2 * (threadIdx.x & 63)];
  int e = (v >> 7) & 0xFF;
  unsigned long long m = __ballot(e >= 100 && e <= 130);
  return __popcll(m) < 48 ? 1 : 0;
}

// direct global->LDS 16B (per-lane gptr, wave-uniform LDS base; HW scatters
// lane i -> base + i*16B)
__device__ __forceinline__ void gload_lds16(const void* g, void* s) {
  __builtin_amdgcn_global_load_lds(
      (const __attribute__((address_space(1))) unsigned int*)(g),
      (__attribute__((address_space(3))) unsigned int*)(s), 16, 0, 0);
}

// ---------------------------------------------------------------------------
// LDS swizzles (16B-granule XOR over 8-granule (128 B) rows)
// ---------------------------------------------------------------------------
__device__ __forceinline__ unsigned short* stg(unsigned short* buf, int r, int u) {
  return buf + r * 64 + ((u ^ (r & 7)) << 3);
}
__device__ __forceinline__ const unsigned short* stgc(const unsigned short* buf, int r, int u) {
  return buf + r * 64 + ((u ^ (r & 7)) << 3);
}
__device__ __forceinline__ int sw_idx(int r, int c) {
  return r * 128 + ((((c >> 3) ^ (r & 7)) << 3) | (c & 7));
}

// 8-element bf16 fragment load from global (with fp32->bf16 convert)
template <typename T>
__device__ __forceinline__ s16x8 load_frag8(const T* p);
template <>
__device__ __forceinline__ s16x8 load_frag8<float>(const float* p) {
  const float4* q = reinterpret_cast<const float4*>(p);
  float4 a = q[0], b = q[1];
  union { unsigned short u[8]; s16x8 w; } t;
  t.u[0] = f2bf(a.x); t.u[1] = f2bf(a.y); t.u[2] = f2bf(a.z); t.u[3] = f2bf(a.w);
  t.u[4] = f2bf(b.x); t.u[5] = f2bf(b.y); t.u[6] = f2bf(b.z); t.u[7] = f2bf(b.w);
  return t.w;
}
template <>
__device__ __forceinline__ s16x8 load_frag8<__hip_bfloat16>(const __hip_bfloat16* p) {
  return *reinterpret_cast<const s16x8*>(p);
}

// 16-element (along K) register chunk, for the fallback path
template <typename T> struct RegChunk;
template <> struct RegChunk<float> {
  float4 v[4];
  __device__ __forceinline__ void load(const float* p) {
    const float4* q = reinterpret_cast<const float4*>(p);
    v[0] = q[0]; v[1] = q[1]; v[2] = q[2]; v[3] = q[3];
  }
  __device__ __forceinline__ void store(unsigned short* d) {
    union { unsigned short u[16]; s16x8 w[2]; } t;
    const float* f = reinterpret_cast<const float*>(v);
#pragma unroll
    for (int i = 0; i < 16; ++i) t.u[i] = f2bf(f[i]);
    reinterpret_cast<s16x8*>(d)[0] = t.w[0];
    reinterpret_cast<s16x8*>(d)[1] = t.w[1];
  }
  __device__ __forceinline__ void store2(unsigned short* d0, unsigned short* d1) {
    union { unsigned short u[16]; s16x8 w[2]; } t;
    const float* f = reinterpret_cast<const float*>(v);
#pragma unroll
    for (int i = 0; i < 16; ++i) t.u[i] = f2bf(f[i]);
    *reinterpret_cast<s16x8*>(d0) = t.w[0];
    *reinterpret_cast<s16x8*>(d1) = t.w[1];
  }
};
template <> struct RegChunk<__hip_bfloat16> {
  s16x8 v[2];
  __device__ __forceinline__ void load(const __hip_bfloat16* p) {
    const s16x8* q = reinterpret_cast<const s16x8*>(p);
    v[0] = q[0]; v[1] = q[1];
  }
  __device__ __forceinline__ void store(unsigned short* d) {
    reinterpret_cast<s16x8*>(d)[0] = v[0];
    reinterpret_cast<s16x8*>(d)[1] = v[1];
  }
  __device__ __forceinline__ void store2(unsigned short* d0, unsigned short* d1) {
    *reinterpret_cast<s16x8*>(d0) = v[0];
    *reinterpret_cast<s16x8*>(d1) = v[1];
  }
};

// ===========================================================================
// NEW PATH
// ===========================================================================

// conv region element offsets (bf16 elems) — used ONLY in the fp32 case
#define CINP 0
#define CQ   16777216
#define CWKV 16908288
#define CWQ  17432576
#define CBKV 17694720
#define CBQ  17695744
#define CTOT 17696256

// ---------------------------------------------------------------------------
// k_conv: fp32 case -> convert everything to bf16 into ws. bf16 case -> no-op
// (downstream kernels read the original buffers directly).
// ---------------------------------------------------------------------------
__global__ __launch_bounds__(256) void k_conv(const void* inputs, const void* queries,
                                              const void* Wkv, const void* Wq,
                                              const void* bkv, const void* bq,
                                              unsigned short* __restrict__ dst) {
  const int fp32 = detect_fp32((const unsigned short*)inputs);
  if (!fp32) return;  // zero-copy: originals are already bf16
  const int bid = blockIdx.x, tid = threadIdx.x;
  if (bid < 2048) {
    // inputs: 2,097,152 units = 2048 blocks x 1024 units, 4/thread
    size_t u = (size_t)bid * 1024 + tid;
#pragma unroll
    for (int k = 0; k < 4; ++k, u += 256) {
      size_t e = u * 8;
      s16x8 v = load_frag8<float>((const float*)inputs + e);
      *reinterpret_cast<s16x8*>(dst + e) = v;
    }
  } else {
    // tail: 114,880 units over 72 blocks
    size_t i8 = (size_t)(bid - 2048) * 256 + tid;
    for (; i8 < 114880; i8 += (size_t)72 * 256) {
      size_t e = CQ + i8 * 8;
      const void* src;
      size_t off;
      if (e < CWKV) { src = queries; off = e - CQ; }
      else if (e < CWQ) { src = Wkv; off = e - CWKV; }
      else if (e < CBKV) { src = Wq; off = e - CWQ; }
      else if (e < CBQ) { src = bkv; off = e - CBKV; }
      else { src = bq; off = e - CBQ; }
      s16x8 v = load_frag8<float>((const float*)src + off);
      *reinterpret_cast<s16x8*>(dst + e) = v;
    }
  }
}

// ---------------------------------------------------------------------------
// k_gemm2: bf16 128x128-tile GEMM via global_load_lds (m97 structure).
// R14: REVERTED to R12 single-buffered 32 KiB form (verified 47.5 us,
// 0 bank conflicts; R13's dbuf traded occupancy for pipelining at a loss).
// MFMA 16x16x32_bf16 layouts (HW-verified):
//   A: m=lane&15, k=quad*8+j ; B: n=lane&15, k=quad*8+j ;
//   D: col=lane&15, row=quad*4+reg
// ---------------------------------------------------------------------------
__global__ __launch_bounds__(256) void k_gemm2(const unsigned short* __restrict__ c,
                                               const void* inputs, const void* queries,
                                               const void* Wkv, const void* Wq,
                                               const void* bkv, const void* bq,
                                               unsigned short* __restrict__ kv,
                                               unsigned short* __restrict__ qws) {
  __shared__ unsigned short Ab[128 * 64];  // 16 KiB
  __shared__ unsigned short Bb[128 * 64];  // 16 KiB

  const int fp32 = detect_fp32((const unsigned short*)inputs);

  // XCD-bijective swizzle (2056 = 8*257): consecutive t on one XCD ->
  // the 8 Nt-blocks of an Mt-panel share the A-panel in that XCD's L2.
  const int bid = blockIdx.x;
  const int t = (bid & 7) * 257 + (bid >> 3);
  const unsigned short *A, *W, *bias;
  unsigned short* dst;
  int dstride, Mt, Nt;
  if (t < 2048) {
    if (fp32) { A = c + CINP; W = c + CWKV; bias = c + CBKV; }
    else {
      A = (const unsigned short*)inputs;
      W = (const unsigned short*)Wkv;
      bias = (const unsigned short*)bkv;
    }
    dst = kv; dstride = 1024; Mt = t >> 3; Nt = t & 7;
  } else {
    const int tq = t - 2048;
    if (fp32) { A = c + CQ; W = c + CWQ; bias = c + CBQ; }
    else {
      A = (const unsigned short*)queries;
      W = (const unsigned short*)Wq;
      bias = (const unsigned short*)bq;
    }
    dst = qws; dstride = 512; Mt = tq >> 2; Nt = tq & 3;
  }

  const int tid = threadIdx.x;
  const int w = tid >> 6, l = tid & 63;
  const int quad = l >> 4, l16 = l & 15;
  const int wr = (w >> 1) * 64, wc = (w & 1) * 64;

  // global_load_lds: lane l -> LDS base + l*16B (row lrow=l>>3, granule l&7);
  // source granule pre-swizzled so swizzled ds_read_b128 is conflict-free.
  const int lrow = l >> 3;
  const int gsw = (l & 7) ^ lrow;

  const f32x4 zero4 = {0.f, 0.f, 0.f, 0.f};
  f32x4 acc[4][4];
#pragma unroll
  for (int i = 0; i < 4; ++i)
#pragma unroll
    for (int j = 0; j < 4; ++j) acc[i][j] = zero4;

  const size_t arow0 = (size_t)(Mt * 128) * 512;
  const size_t brow0 = (size_t)(Nt * 128) * 512;

#pragma unroll
  for (int k0 = 0; k0 < 512; k0 += 64) {
    __syncthreads();  // previous compute done; LDS free
#pragma unroll
    for (int k = 0; k < 4; ++k) {
      const int row = w * 32 + k * 8 + lrow;          // 0..127
      const int srcc = k0 + gsw * 8;                  // swizzled source col
      gload_lds16(A + arow0 + (size_t)row * 512 + srcc, Ab + (w * 32 + k * 8) * 64);
      gload_lds16(W + brow0 + (size_t)row * 512 + srcc, Bb + (w * 32 + k * 8) * 64);
    }
    __syncthreads();  // implicit vmcnt(0) drain -> tiles resident
#pragma unroll
    for (int kk2 = 0; kk2 < 2; ++kk2) {
      s16x8 af[4], bfr[4];
#pragma unroll
      for (int i = 0; i < 4; ++i)
        af[i] = *reinterpret_cast<const s16x8*>(stgc(Ab, wr + i * 16 + l16, kk2 * 4 + quad));
#pragma unroll
      for (int j = 0; j < 4; ++j)
        bfr[j] = *reinterpret_cast<const s16x8*>(stgc(Bb, wc + j * 16 + l16, kk2 * 4 + quad));
#pragma unroll
      for (int i = 0; i < 4; ++i)
#pragma unroll
        for (int j = 0; j < 4; ++j) acc[i][j] = mfma16(af[i], bfr[j], acc[i][j]);
    }
  }

#pragma unroll
  for (int j = 0; j < 4; ++j) {
    float bb = bf2f(bias[Nt * 128 + wc + j * 16 + l16]);
#pragma unroll
    for (int i = 0; i < 4; ++i)
#pragma unroll
      for (int rg = 0; rg < 4; ++rg) {
        int row = Mt * 128 + wr + i * 16 + quad * 4 + rg;
        int col = Nt * 128 + wc + j * 16 + l16;
        dst[(size_t)row * dstride + col] = f2bf(acc[i][j][rg] + bb);
      }
  }
}

// ---------------------------------------------------------------------------
// k_attn: grid (32 stile, 8 b, 2 hpi-pair), 512 thr. Per head-pair: stage
// K-tile [128s][128d] + V^T [128d][128s] from kv, u-GEMM/P/den, num-GEMM.
// R14: LDS exactly 80 KiB (denL removed; den via atomicAdd on zeroed
// den_part) -> 2 blocks/CU; 512 blocks so staging overlaps compute across
// co-resident blocks. T14 named-reg prefetch; u32-paired V^T staging.
// ---------------------------------------------------------------------------
template <typename T>
__device__ __forceinline__ void attn_body(const unsigned short* __restrict__ kv,
                                          const unsigned short* __restrict__ qws,
                                          const T* __restrict__ masks,
                                          float* __restrict__ num_part,
                                          float* __restrict__ den_part,
                                          unsigned short* kvb, unsigned short* vtb,
                                          unsigned short* Pb) {
  const int stile = blockIdx.x, b = blockIdx.y;
  const int hp0 = blockIdx.z * 2;  // this block's two head-pairs
  const int s0 = stile * 128;
  const int tid = threadIdx.x;
  const int w = tid >> 6, l = tid & 63;
  const int quad = l >> 4, l16 = l & 15;
  const int hh = w >> 2, mt = (w >> 1) & 1, sh = w & 1, dh = w & 1;
  // K staging mapping: thread -> (row sr2, 32-col chunk c0)
  const int sr2 = tid >> 2, c0 = (tid & 3) * 32;
  // V staging mapping: thread -> (row pair rp2, 16-col chunk cb)
  const int rp2 = (tid >> 3) * 2;       // 0,2,..,126
  const int cb = (tid & 7) * 16;
  const f32x4 zero4 = {0.f, 0.f, 0.f, 0.f};
  const float scale = 0.044194173824159216f;  // 1/sqrt(512)
  const int bstile = b * 32 + stile;

  const unsigned short* kbase = kv + ((size_t)(b * 4096 + s0 + sr2)) * 1024;
  const unsigned short* vbase0 = kv + ((size_t)(b * 4096 + s0 + rp2)) * 1024 + 512;
  const unsigned short* vbase1 = vbase0 + 1024;

  // prefetch registers (named; loop below fully unrolled)
  s16x8 kp0, kp1, kp2, kp3, va0, va1, vb0, vb1;
  auto loadKV = [&](int hpi) {
    const unsigned short* kr = kbase + hpi * 128 + c0;
    kp0 = *reinterpret_cast<const s16x8*>(kr);
    kp1 = *reinterpret_cast<const s16x8*>(kr + 8);
    kp2 = *reinterpret_cast<const s16x8*>(kr + 16);
    kp3 = *reinterpret_cast<const s16x8*>(kr + 24);
    const unsigned short* v0 = vbase0 + hpi * 128 + cb;
    const unsigned short* v1 = vbase1 + hpi * 128 + cb;
    va0 = *reinterpret_cast<const s16x8*>(v0);
    va1 = *reinterpret_cast<const s16x8*>(v0 + 8);
    vb0 = *reinterpret_cast<const s16x8*>(v1);
    vb1 = *reinterpret_cast<const s16x8*>(v1 + 8);
  };
  loadKV(hp0);

#pragma unroll
  for (int hi = 0; hi < 2; ++hi) {
    const int hpi = hp0 + hi;
    // ---- stage K (swizzled rowmajor, b128 writes) ----
    *reinterpret_cast<s16x8*>(&kvb[sw_idx(sr2, c0)]) = kp0;
    *reinterpret_cast<s16x8*>(&kvb[sw_idx(sr2, c0 + 8)]) = kp1;
    *reinterpret_cast<s16x8*>(&kvb[sw_idx(sr2, c0 + 16)]) = kp2;
    *reinterpret_cast<s16x8*>(&kvb[sw_idx(sr2, c0 + 24)]) = kp3;
    // ---- stage V^T: rows rp2, rp2+1 packed into u32 per transposed elem ----
    // (sw_idx(c, rp2)+1 == sw_idx(c, rp2+1) since rp2 is even: u32-safe)
    {
      union { s16x8 w; unsigned short u[8]; } a0, a1, b0, b1;
      a0.w = va0; a1.w = va1; b0.w = vb0; b1.w = vb1;
#pragma unroll
      for (int e = 0; e < 8; ++e) {
        unsigned int p0 = (unsigned int)a0.u[e] | ((unsigned int)b0.u[e] << 16);
        *reinterpret_cast<unsigned int*>(&vtb[sw_idx(cb + e, rp2)]) = p0;
        unsigned int p1 = (unsigned int)a1.u[e] | ((unsigned int)b1.u[e] << 16);
        *reinterpret_cast<unsigned int*>(&vtb[sw_idx(cb + 8 + e, rp2)]) = p1;
      }
    }
    // ---- T14: issue next head-pair's global loads now ----
    if (hi == 0) loadKV(hpi + 1);
    __syncthreads();

    // ---- u-GEMM + P + den: wave -> (hh, mt, sh) ----
    {
      f32x4 ua[4];
#pragma unroll
      for (int j = 0; j < 4; ++j) ua[j] = zero4;
#pragma unroll
      for (int kk = 0; kk < 2; ++kk) {
        s16x8 aq = *reinterpret_cast<const s16x8*>(
            &qws[((size_t)(b * 32 + mt * 16 + l16)) * 512 + hpi * 128 + hh * 64 + kk * 32 +
                 quad * 8]);
#pragma unroll
        for (int j = 0; j < 4; ++j) {
          s16x8 bk = *reinterpret_cast<const s16x8*>(
              &kvb[sw_idx(sh * 64 + j * 16 + l16, hh * 64 + kk * 32 + quad * 8)]);
          ua[j] = mfma16(aq, bk, ua[j]);
        }
      }
      float dsum[4] = {0.f, 0.f, 0.f, 0.f};
#pragma unroll
      for (int j = 0; j < 4; ++j) {
        int scol = sh * 64 + j * 16 + l16;
        float mask = tofl(masks[(size_t)b * 4096 + s0 + scol]);
#pragma unroll
        for (int rg = 0; rg < 4; ++rg) {
          int qrow = mt * 16 + quad * 4 + rg;
          float uv = ua[j][rg] * scale;
          float e = uv > 0.f ? uv : (__expf(uv) - 1.f);  // elu (low clip dead)
          e = fminf(e, 15.f);
          float p = __expf(e) * mask;
          unsigned short pu = f2bf(p);
          Pb[sw_idx(hh * 32 + qrow, scol)] = pu;
          dsum[rg] += bf2f(pu);  // sum the ROUNDED value num-GEMM uses
        }
      }
      // den: 16-lane shuffle reduce, then atomicAdd (2 waves/location,
      // den_part pre-zeroed by memset) — no LDS needed.
#pragma unroll
      for (int rg = 0; rg < 4; ++rg) {
        float s = dsum[rg];
        s += __shfl_xor(s, 1);
        s += __shfl_xor(s, 2);
        s += __shfl_xor(s, 4);
        s += __shfl_xor(s, 8);
        if (l16 == 0) {
          int qrow = mt * 16 + quad * 4 + rg;
          atomicAdd(&den_part[((size_t)bstile * 32 + qrow) * 8 + hpi * 2 + hh], s);
        }
      }
    }
    __syncthreads();  // Pb complete

    // ---- num-GEMM: wave -> (hh, mt, dh) ----
    {
      f32x4 na0 = zero4, na1 = zero4;
#pragma unroll
      for (int kk = 0; kk < 4; ++kk) {
        s16x8 ap = *reinterpret_cast<const s16x8*>(
            &Pb[sw_idx(hh * 32 + mt * 16 + l16, kk * 32 + quad * 8)]);
        s16x8 bv0 = *reinterpret_cast<const s16x8*>(
            &vtb[sw_idx(hh * 64 + dh * 32 + l16, kk * 32 + quad * 8)]);
        s16x8 bv1 = *reinterpret_cast<const s16x8*>(
            &vtb[sw_idx(hh * 64 + dh * 32 + 16 + l16, kk * 32 + quad * 8)]);
        na0 = mfma16(ap, bv0, na0);
        na1 = mfma16(ap, bv1, na1);
      }
#pragma unroll
      for (int rg = 0; rg < 4; ++rg) {
        int qrow = mt * 16 + quad * 4 + rg;
        size_t base = ((size_t)bstile * 32 + qrow) * 512 + (hpi * 2 + hh) * 64 + dh * 32;
        num_part[base + l16] = na0[rg];
        num_part[base + 16 + l16] = na1[rg];
      }
    }
    __syncthreads();  // before next hi overwrites kvb/vtb/Pb
  }
}

__global__ __launch_bounds__(512, 4) void k_attn(const unsigned short* __restrict__ kv,
                                                 const unsigned short* __restrict__ qws,
                                                 const void* masks,
                                                 float* __restrict__ num_part,
                                                 float* __restrict__ den_part,
                                                 const unsigned short* __restrict__ det) {
  __shared__ unsigned short kvb[128 * 128];  // 32 KiB
  __shared__ unsigned short vtb[128 * 128];  // 32 KiB
  __shared__ unsigned short Pb[64 * 128];    // 16 KiB  -> total exactly 80 KiB
  if (detect_fp32(det))
    attn_body<float>(kv, qws, (const float*)masks, num_part, den_part, kvb, vtb, Pb);
  else
    attn_body<__hip_bfloat16>(kv, qws, (const __hip_bfloat16*)masks, num_part, den_part,
                              kvb, vtb, Pb);
}

// ---------------------------------------------------------------------------
__global__ __launch_bounds__(256) void k_final(const float* __restrict__ num_part,
                                               const float* __restrict__ den_part, void* out,
                                               const unsigned short* __restrict__ det) {
  int i = blockIdx.x * 256 + threadIdx.x;
  int b = i >> 14, qhd = i & 16383;
  int q = (i >> 9) & 31, h = (i >> 6) & 7;
  float sn = 0.f, sd = 0.f;
#pragma unroll 4
  for (int st = 0; st < 32; ++st) {
    sn += num_part[(((size_t)(b * 32 + st)) << 14) + qhd];
    sd += den_part[((size_t)(b * 32 + st) * 32 + q) * 8 + h];
  }
  float v = sn / sd;
  if (detect_fp32(det))
    ((float*)out)[i] = v;
  else
    ((__hip_bfloat16*)out)[i] = __float2bfloat16(v);
}

// ===========================================================================
// FALLBACK PATH (R1-verified, 231 us) — used only if ws is too small.
// ===========================================================================
template <typename T>
__device__ __forceinline__ void qproj_body_fb(const T* __restrict__ queries,
                                              const T* __restrict__ Wq,
                                              const T* __restrict__ bq,
                                              unsigned short* __restrict__ qws,
                                              unsigned short* Abuf, unsigned short* Bbuf) {
  const int Mt = blockIdx.x, Nt = blockIdx.y;
  const int tid = threadIdx.x;
  const int w = tid >> 6, l = tid & 63;
  const int quad = l >> 4, l16 = l & 15;
  const int wr = (w >> 1) * 64, wc = (w & 1) * 64;
  const int r_st = tid >> 1;
  const int kk_st = (tid & 1) * 16;
  const T* Asrc = queries + ((size_t)(Mt * 128 + r_st)) * 512 + kk_st;
  const T* Bsrc = Wq + ((size_t)(Nt * 128 + r_st)) * 512 + kk_st;

  const f32x4 zero4 = {0.f, 0.f, 0.f, 0.f};
  f32x4 acc[4][4];
#pragma unroll
  for (int i = 0; i < 4; ++i)
#pragma unroll
    for (int j = 0; j < 4; ++j) acc[i][j] = zero4;

  RegChunk<T> ra, rb;
  ra.load(Asrc);
  rb.load(Bsrc);
  for (int k0 = 0; k0 < 512; k0 += 32) {
    __syncthreads();
    ra.store(&Abuf[r_st * 32 + kk_st]);
    rb.store(&Bbuf[r_st * 32 + kk_st]);
    if (k0 + 32 < 512) {
      ra.load(Asrc + k0 + 32);
      rb.load(Bsrc + k0 + 32);
    }
    __syncthreads();
    s16x8 af[4], bfr[4];
#pragma unroll
    for (int i = 0; i < 4; ++i)
      af[i] = *reinterpret_cast<const s16x8*>(&Abuf[(wr + i * 16 + l16) * 32 + quad * 8]);
#pragma unroll
    for (int j = 0; j < 4; ++j)
      bfr[j] = *reinterpret_cast<const s16x8*>(&Bbuf[(wc + j * 16 + l16) * 32 + quad * 8]);
#pragma unroll
    for (int i = 0; i < 4; ++i)
#pragma unroll
      for (int j = 0; j < 4; ++j) acc[i][j] = mfma16(af[i], bfr[j], acc[i][j]);
  }
#pragma unroll
  for (int j = 0; j < 4; ++j) {
    float bb = tofl(bq[Nt * 128 + wc + j * 16 + l16]);
#pragma unroll
    for (int i = 0; i < 4; ++i)
#pragma unroll
      for (int rg = 0; rg < 4; ++rg) {
        int row = Mt * 128 + wr + i * 16 + quad * 4 + rg;
        int col = Nt * 128 + wc + j * 16 + l16;
        qws[(size_t)row * 512 + col] = f2bf(acc[i][j][rg] + bb);
      }
  }
}

__global__ __launch_bounds__(256) void k_qproj_fb(const void* queries, const void* Wq,
                                                  const void* bq, unsigned short* qws,
                                                  const unsigned short* __restrict__ det) {
  __shared__ unsigned short Abuf[128 * 32];
  __shared__ unsigned short Bbuf[128 * 32];
  if (detect_fp32(det))
    qproj_body_fb<float>((const float*)queries, (const float*)Wq, (const float*)bq, qws,
                         Abuf, Bbuf);
  else
    qproj_body_fb<__hip_bfloat16>((const __hip_bfloat16*)queries,
                                  (const __hip_bfloat16*)Wq, (const __hip_bfloat16*)bq, qws,
                                  Abuf, Bbuf);
}

template <typename T>
__device__ __forceinline__ void fused_body_fb(
    const T* __restrict__ inputs, const T* __restrict__ masks, const T* __restrict__ Wkv,
    const T* __restrict__ bkv, const unsigned short* __restrict__ qws,
    float* __restrict__ num, float* __restrict__ den, unsigned short* Abuf,
    unsigned short* Bbuf, unsigned short* kvbuf, unsigned short* vbuf,
    unsigned short* Pbuf) {
  const int stile = blockIdx.x;
  const int b = blockIdx.y;
  const int hp = blockIdx.z;
  const int s0 = stile * 128;
  const int tid = threadIdx.x;
  const int w = tid >> 6;
  const int l = tid & 63;
  const int quad = l >> 4;
  const int l16 = l & 15;
  const int which = w >> 2;
  const int wr = ((w >> 1) & 1) * 64;
  const int wc = (w & 1) * 64;

  const f32x4 zero4 = {0.f, 0.f, 0.f, 0.f};
  f32x4 acc[4][4];
#pragma unroll
  for (int i = 0; i < 4; ++i)
#pragma unroll
    for (int j = 0; j < 4; ++j) acc[i][j] = zero4;

  const int sr = tid >> 2;
  const int sc = tid & 3;
  const T* Asrc = inputs + ((size_t)(b * 4096 + s0 + sr)) * 512 + sc * 16;
  const T* BKs = Wkv + ((size_t)(hp * 128 + sr)) * 512 + sc * 16;
  const T* BVs = Wkv + ((size_t)(512 + hp * 128 + sr)) * 512 + sc * 16;
  unsigned short* ad0 = stg(Abuf, sr, sc * 2);
  unsigned short* ad1 = stg(Abuf, sr, sc * 2 + 1);
  unsigned short* bk0 = stg(Bbuf, sr, sc * 2);
  unsigned short* bk1 = stg(Bbuf, sr, sc * 2 + 1);
  unsigned short* bv0 = stg(Bbuf, 128 + sr, sc * 2);
  unsigned short* bv1 = stg(Bbuf, 128 + sr, sc * 2 + 1);

  RegChunk<T> ra0, ra1, rbk, rbv;
  ra0.load(Asrc);
  ra1.load(Asrc + 64);
  rbk.load(BKs);
  rbv.load(BVs);

#pragma unroll
  for (int it2 = 0; it2 < 4; ++it2) {
#pragma unroll
    for (int ph = 0; ph < 2; ++ph) {
      const int it = it2 * 2 + ph;
      RegChunk<T>& ra = ph ? ra1 : ra0;
      __syncthreads();
      ra.store2(ad0, ad1);
      rbk.store2(bk0, bk1);
      rbv.store2(bv0, bv1);
      if (it < 6) ra.load(Asrc + (it + 2) * 64);
      if (it < 7) {
        rbk.load(BKs + (it + 1) * 64);
        rbv.load(BVs + (it + 1) * 64);
      }
      __syncthreads();
#pragma unroll
      for (int kk2 = 0; kk2 < 2; ++kk2) {
        s16x8 af[4], bfr[4];
#pragma unroll
        for (int i = 0; i < 4; ++i)
          af[i] = *reinterpret_cast<const s16x8*>(stgc(Abuf, wr + i * 16 + l16, kk2 * 4 + quad));
#pragma unroll
        for (int j = 0; j < 4; ++j)
          bfr[j] = *reinterpret_cast<const s16x8*>(
              stgc(Bbuf, which * 128 + wc + j * 16 + l16, kk2 * 4 + quad));
#pragma unroll
        for (int i = 0; i < 4; ++i)
#pragma unroll
          for (int j = 0; j < 4; ++j) acc[i][j] = mfma16(af[i], bfr[j], acc[i][j]);
      }
    }
  }

#pragma unroll
  for (int j = 0; j < 4; ++j) {
    float bb = tofl(bkv[which * 512 + hp * 128 + wc + j * 16 + l16]);
#pragma unroll
    for (int i = 0; i < 4; ++i)
#pragma unroll
      for (int rg = 0; rg < 4; ++rg) {
        int sl = wr + i * 16 + quad * 4 + rg;
        int c = wc + j * 16 + l16;
        unsigned short bv = f2bf(acc[i][j][rg] + bb);
        if (which == 0)
          kvbuf[sw_idx(sl, c)] = bv;
        else
          vbuf[sw_idx(c, sl)] = bv;
      }
  }
  __syncthreads();

  const int hh = w >> 2, mt = (w >> 1) & 1, sh = w & 1;
  {
    f32x4 ua[4];
#pragma unroll
    for (int j = 0; j < 4; ++j) ua[j] = zero4;
#pragma unroll
    for (int kk = 0; kk < 2; ++kk) {
      s16x8 aq = *reinterpret_cast<const s16x8*>(
          qws + ((size_t)(b * 32 + mt * 16 + l16)) * 512 + hp * 128 + hh * 64 + kk * 32 +
          quad * 8);
#pragma unroll
      for (int j = 0; j < 4; ++j) {
        s16x8 bk = *reinterpret_cast<const s16x8*>(
            &kvbuf[sw_idx(sh * 64 + j * 16 + l16, hh * 64 + kk * 32 + quad * 8)]);
        ua[j] = mfma16(aq, bk, ua[j]);
      }
    }
    const float scale = 0.044194173824159216f;
    float dsum[4] = {0.f, 0.f, 0.f, 0.f};
#pragma unroll
    for (int j = 0; j < 4; ++j) {
      int scol = sh * 64 + j * 16 + l16;
      float mask = tofl(masks[(size_t)b * 4096 + s0 + scol]);
#pragma unroll
      for (int rg = 0; rg < 4; ++rg) {
        int qrow = mt * 16 + quad * 4 + rg;
        float uv = ua[j][rg] * scale;
        float e = uv > 0.f ? uv : (__expf(uv) - 1.f);
        e = fminf(e, 15.f);
        float p = __expf(e) * mask;
        unsigned short pu = f2bf(p);
        Pbuf[sw_idx(hh * 32 + qrow, scol)] = pu;
        dsum[rg] += bf2f(pu);
      }
    }
#pragma unroll
    for (int rg = 0; rg < 4; ++rg) {
      float s = dsum[rg];
      s += __shfl_xor(s, 1);
      s += __shfl_xor(s, 2);
      s += __shfl_xor(s, 4);
      s += __shfl_xor(s, 8);
      if (l16 == 0) {
        int qrow = mt * 16 + quad * 4 + rg;
        atomicAdd(&den[((size_t)(b * 32 + qrow)) * 8 + hp * 2 + hh], s);
      }
    }
  }
  __syncthreads();

  {
    const int dh = w & 1;
    f32x4 na[2];
    na[0] = zero4;
    na[1] = zero4;
#pragma unroll
    for (int kk = 0; kk < 4; ++kk) {
      s16x8 ap = *reinterpret_cast<const s16x8*>(
          &Pbuf[sw_idx(hh * 32 + mt * 16 + l16, kk * 32 + quad * 8)]);
#pragma unroll
      for (int jj = 0; jj < 2; ++jj) {
        int j = dh * 2 + jj;
        s16x8 bv = *reinterpret_cast<const s16x8*>(
            &vbuf[sw_idx(hh * 64 + j * 16 + l16, kk * 32 + quad * 8)]);
        na[jj] = mfma16(ap, bv, na[jj]);
      }
    }
    const int h = hp * 2 + hh;
#pragma unroll
    for (int jj = 0; jj < 2; ++jj) {
      int d = (dh * 2 + jj) * 16 + l16;
#pragma unroll
      for (int rg = 0; rg < 4; ++rg) {
        int qrow = mt * 16 + quad * 4 + rg;
        atomicAdd(&num[(((size_t)(b * 32 + qrow)) * 8 + h) * 64 + d], na[jj][rg]);
      }
    }
  }
}

__global__ __launch_bounds__(512, 2) void k_fused_fb(const void* inputs, const void* masks,
                                                     const void* Wkv, const void* bkv,
                                                     const unsigned short* __restrict__ qws,
                                                     float* __restrict__ num,
                                                     float* __restrict__ den) {
  __shared__ unsigned short Abuf[128 * 64];
  __shared__ unsigned short Bbuf[256 * 64];
  __shared__ unsigned short kvbuf[128 * 128];
  __shared__ unsigned short vbuf[128 * 128];
  __shared__ unsigned short Pbuf[64 * 128];
  if (detect_fp32((const unsigned short*)inputs))
    fused_body_fb<float>((const float*)inputs, (const float*)masks, (const float*)Wkv,
                         (const float*)bkv, qws, num, den, Abuf, Bbuf, kvbuf, vbuf, Pbuf);
  else
    fused_body_fb<__hip_bfloat16>((const __hip_bfloat16*)inputs,
                                  (const __hip_bfloat16*)masks, (const __hip_bfloat16*)Wkv,
                                  (const __hip_bfloat16*)bkv, qws, num, den, Abuf, Bbuf,
                                  kvbuf, vbuf, Pbuf);
}

__global__ __launch_bounds__(256) void k_div_fb(const float* __restrict__ num,
                                                const float* __restrict__ den, void* out,
                                                const unsigned short* __restrict__ det) {
  int i = blockIdx.x * 256 + threadIdx.x;
  float v = num[i] / den[i >> 6];
  if (detect_fp32(det))
    ((float*)out)[i] = v;
  else
    ((__hip_bfloat16*)out)[i] = __float2bfloat16(v);
}

// ---------------------------------------------------------------------------
extern "C" void kernel_launch(void* const* d_in, const int* in_sizes, int n_in,
                              void* d_out, int out_size, void* d_ws, size_t ws_size,
                              hipStream_t stream) {
  // d_in: 0 inputs, 1 queries, 2 masks, 3 Wkv, 4 bkv, 5 Wq, 6 bq
  char* ws = (char*)d_ws;
  if (ws_size >= 119802880) {
    // NEW path. ws (bytes):
    //   [0]         conv region (bf16, fp32 case only; 35,392,512 B)
    //   [35392512]  kv  bf16 [32768][1024]  (67,108,864 B)
    //   [102501376] qws bf16 [256][512]     (262,144 B)
    //   [102763520] num_part f32            (16,777,216 B)
    //   [119540736] den_part f32            (262,144 B)
    unsigned short* conv = (unsigned short*)ws;
    unsigned short* kv = (unsigned short*)(ws + 35392512);
    unsigned short* qws = (unsigned short*)(ws + 102501376);
    float* num_part = (float*)(ws + 102763520);
    float* den_part = (float*)(ws + 119540736);

    hipMemsetAsync(den_part, 0, 262144, stream);  // den accumulated via atomics
    k_conv<<<2120, 256, 0, stream>>>(d_in[0], d_in[1], d_in[3], d_in[5], d_in[4], d_in[6],
                                     conv);
    k_gemm2<<<2056, 256, 0, stream>>>(conv, d_in[0], d_in[1], d_in[3], d_in[5], d_in[4],
                                      d_in[6], kv, qws);
    k_attn<<<dim3(32, 8, 2), 512, 0, stream>>>(kv, qws, d_in[2], num_part, den_part,
                                               (const unsigned short*)d_in[0]);
    k_final<<<512, 256, 0, stream>>>(num_part, den_part, d_out,
                                     (const unsigned short*)d_in[0]);
  } else if (ws_size >= 802816) {
    // FALLBACK (R1 path). ws: [1024] den ; [16384] num ; [540672] qws
    float* den = (float*)(ws + 1024);
    float* num = (float*)(ws + 16384);
    unsigned short* qws = (unsigned short*)(ws + 540672);

    hipMemsetAsync(d_ws, 0, 540672, stream);
    dim3 gq(2, 4);
    k_qproj_fb<<<gq, 256, 0, stream>>>(d_in[1], d_in[5], d_in[6], qws,
                                       (const unsigned short*)d_in[0]);
    dim3 g2(32, 8, 4);
    k_fused_fb<<<g2, 512, 0, stream>>>(d_in[0], d_in[2], d_in[3], d_in[4], qws, num, den);
    k_div_fb<<<512, 256, 0, stream>>>(num, den, d_out, (const unsigned short*)d_in[0]);
  }
}

// Round 11
// 183.812 us; speedup vs baseline: 1.0273x; 1.0273x over previous
//
#include <hip/hip_runtime.h>
#include <hip/hip_bf16.h>

// ---------------------------------------------------------------------------
// MultiHeadAttention for MI355X (gfx950)
// B=8 S=4096 Q=32 H=8 D=64 IN=512 NKV=1024
// R15: k_gemm2 epilogue -> staged through the (dead) 32 KiB staging arena
//      with a bank-swizzle, then fully-coalesced b128 row stores. Fixes the
//      ~30% HBM write amplification (WRITE_SIZE 84 vs 64.3 MB ideal) from
//      the old 64-scalar-u16-stores/thread epilogue. gemm2 is measured
//      memory-rate-bound at ~2.4 TB/s (dur tracks hbm_bytes across R10-R14),
//      so bytes saved = time saved. Everything else unchanged from R14.
// Fallback: R1-verified 3-kernel path if ws_size < 120 MB.
// ---------------------------------------------------------------------------

typedef float f32x4 __attribute__((ext_vector_type(4)));
typedef short s16x8 __attribute__((ext_vector_type(8)));

__device__ __forceinline__ unsigned short f2bf(float f) {
  union { __hip_bfloat16 h; unsigned short u; } cv;
  cv.h = __float2bfloat16(f);
  return cv.u;
}
__device__ __forceinline__ float bf2f(unsigned short u) {
  union { unsigned short u; __hip_bfloat16 h; } cv;
  cv.u = u;
  return __bfloat162float(cv.h);
}
__device__ __forceinline__ float tofl(float v) { return v; }
__device__ __forceinline__ float tofl(__hip_bfloat16 v) { return __bfloat162float(v); }

__device__ __forceinline__ f32x4 mfma16(s16x8 a, s16x8 b, f32x4 c) {
  return __builtin_amdgcn_mfma_f32_16x16x32_bf16(a, b, c, 0, 0, 0);
}

// dtype detection (1 = fp32, 0 = bf16)
__device__ __forceinline__ int detect_fp32(const unsigned short* __restrict__ in16) {
  unsigned short v = in16[2 * (threadIdx.x & 63)];
  int e = (v >> 7) & 0xFF;
  unsigned long long m = __ballot(e >= 100 && e <= 130);
  return __popcll(m) < 48 ? 1 : 0;
}

// direct global->LDS 16B (per-lane gptr, wave-uniform LDS base; HW scatters
// lane i -> base + i*16B)
__device__ __forceinline__ void gload_lds16(const void* g, void* s) {
  __builtin_amdgcn_global_load_lds(
      (const __attribute__((address_space(1))) unsigned int*)(g),
      (__attribute__((address_space(3))) unsigned int*)(s), 16, 0, 0);
}

// ---------------------------------------------------------------------------
// LDS swizzles (16B-granule XOR over 8-granule (128 B) rows)
// ---------------------------------------------------------------------------
__device__ __forceinline__ unsigned short* stg(unsigned short* buf, int r, int u) {
  return buf + r * 64 + ((u ^ (r & 7)) << 3);
}
__device__ __forceinline__ const unsigned short* stgc(const unsigned short* buf, int r, int u) {
  return buf + r * 64 + ((u ^ (r & 7)) << 3);
}
__device__ __forceinline__ int sw_idx(int r, int c) {
  return r * 128 + ((((c >> 3) ^ (r & 7)) << 3) | (c & 7));
}
// Epilogue swizzle for the 128x128 C-tile: slot = (c>>3) ^ ((r>>1)&7).
// Bijective per row (XOR of low 3 slot bits); (r>>1) makes the 4 quads of a
// C-spill store instruction land in 4 distinct bank-groups (2 lanes/bank).
__device__ __forceinline__ int esw(int r, int c) {
  return r * 128 + ((((c >> 3) ^ ((r >> 1) & 7)) << 3) | (c & 7));
}

// 8-element bf16 fragment load from global (with fp32->bf16 convert)
template <typename T>
__device__ __forceinline__ s16x8 load_frag8(const T* p);
template <>
__device__ __forceinline__ s16x8 load_frag8<float>(const float* p) {
  const float4* q = reinterpret_cast<const float4*>(p);
  float4 a = q[0], b = q[1];
  union { unsigned short u[8]; s16x8 w; } t;
  t.u[0] = f2bf(a.x); t.u[1] = f2bf(a.y); t.u[2] = f2bf(a.z); t.u[3] = f2bf(a.w);
  t.u[4] = f2bf(b.x); t.u[5] = f2bf(b.y); t.u[6] = f2bf(b.z); t.u[7] = f2bf(b.w);
  return t.w;
}
template <>
__device__ __forceinline__ s16x8 load_frag8<__hip_bfloat16>(const __hip_bfloat16* p) {
  return *reinterpret_cast<const s16x8*>(p);
}

// 16-element (along K) register chunk, for the fallback path
template <typename T> struct RegChunk;
template <> struct RegChunk<float> {
  float4 v[4];
  __device__ __forceinline__ void load(const float* p) {
    const float4* q = reinterpret_cast<const float4*>(p);
    v[0] = q[0]; v[1] = q[1]; v[2] = q[2]; v[3] = q[3];
  }
  __device__ __forceinline__ void store(unsigned short* d) {
    union { unsigned short u[16]; s16x8 w[2]; } t;
    const float* f = reinterpret_cast<const float*>(v);
#pragma unroll
    for (int i = 0; i < 16; ++i) t.u[i] = f2bf(f[i]);
    reinterpret_cast<s16x8*>(d)[0] = t.w[0];
    reinterpret_cast<s16x8*>(d)[1] = t.w[1];
  }
  __device__ __forceinline__ void store2(unsigned short* d0, unsigned short* d1) {
    union { unsigned short u[16]; s16x8 w[2]; } t;
    const float* f = reinterpret_cast<const float*>(v);
#pragma unroll
    for (int i = 0; i < 16; ++i) t.u[i] = f2bf(f[i]);
    *reinterpret_cast<s16x8*>(d0) = t.w[0];
    *reinterpret_cast<s16x8*>(d1) = t.w[1];
  }
};
template <> struct RegChunk<__hip_bfloat16> {
  s16x8 v[2];
  __device__ __forceinline__ void load(const __hip_bfloat16* p) {
    const s16x8* q = reinterpret_cast<const s16x8*>(p);
    v[0] = q[0]; v[1] = q[1];
  }
  __device__ __forceinline__ void store(unsigned short* d) {
    reinterpret_cast<s16x8*>(d)[0] = v[0];
    reinterpret_cast<s16x8*>(d)[1] = v[1];
  }
  __device__ __forceinline__ void store2(unsigned short* d0, unsigned short* d1) {
    *reinterpret_cast<s16x8*>(d0) = v[0];
    *reinterpret_cast<s16x8*>(d1) = v[1];
  }
};

// ===========================================================================
// NEW PATH
// ===========================================================================

// conv region element offsets (bf16 elems) — used ONLY in the fp32 case
#define CINP 0
#define CQ   16777216
#define CWKV 16908288
#define CWQ  17432576
#define CBKV 17694720
#define CBQ  17695744
#define CTOT 17696256

// ---------------------------------------------------------------------------
// k_conv: fp32 case -> convert everything to bf16 into ws. bf16 case -> no-op
// (downstream kernels read the original buffers directly).
// ---------------------------------------------------------------------------
__global__ __launch_bounds__(256) void k_conv(const void* inputs, const void* queries,
                                              const void* Wkv, const void* Wq,
                                              const void* bkv, const void* bq,
                                              unsigned short* __restrict__ dst) {
  const int fp32 = detect_fp32((const unsigned short*)inputs);
  if (!fp32) return;  // zero-copy: originals are already bf16
  const int bid = blockIdx.x, tid = threadIdx.x;
  if (bid < 2048) {
    // inputs: 2,097,152 units = 2048 blocks x 1024 units, 4/thread
    size_t u = (size_t)bid * 1024 + tid;
#pragma unroll
    for (int k = 0; k < 4; ++k, u += 256) {
      size_t e = u * 8;
      s16x8 v = load_frag8<float>((const float*)inputs + e);
      *reinterpret_cast<s16x8*>(dst + e) = v;
    }
  } else {
    // tail: 114,880 units over 72 blocks
    size_t i8 = (size_t)(bid - 2048) * 256 + tid;
    for (; i8 < 114880; i8 += (size_t)72 * 256) {
      size_t e = CQ + i8 * 8;
      const void* src;
      size_t off;
      if (e < CWKV) { src = queries; off = e - CQ; }
      else if (e < CWQ) { src = Wkv; off = e - CWKV; }
      else if (e < CBKV) { src = Wq; off = e - CWQ; }
      else if (e < CBQ) { src = bkv; off = e - CBKV; }
      else { src = bq; off = e - CBQ; }
      s16x8 v = load_frag8<float>((const float*)src + off);
      *reinterpret_cast<s16x8*>(dst + e) = v;
    }
  }
}

// ---------------------------------------------------------------------------
// k_gemm2: bf16 128x128-tile GEMM via global_load_lds (m97 structure,
// single-buffered 32 KiB staging, 0 bank conflicts).
// R15: epilogue staged through the dead staging arena (esw swizzle) and
// written with coalesced b128 row stores (256 B/row-segment, whole sectors).
// MFMA 16x16x32_bf16 layouts (HW-verified):
//   A: m=lane&15, k=quad*8+j ; B: n=lane&15, k=quad*8+j ;
//   D: col=lane&15, row=quad*4+reg
// ---------------------------------------------------------------------------
__global__ __launch_bounds__(256) void k_gemm2(const unsigned short* __restrict__ c,
                                               const void* inputs, const void* queries,
                                               const void* Wkv, const void* Wq,
                                               const void* bkv, const void* bq,
                                               unsigned short* __restrict__ kv,
                                               unsigned short* __restrict__ qws) {
  __shared__ unsigned short arena[128 * 128];  // 32 KiB: Ab|Bb in K-loop,
  unsigned short* Ab = arena;                  // C-tile in epilogue
  unsigned short* Bb = arena + 8192;

  const int fp32 = detect_fp32((const unsigned short*)inputs);

  // XCD-bijective swizzle (2056 = 8*257): consecutive t on one XCD ->
  // the 8 Nt-blocks of an Mt-panel share the A-panel in that XCD's L2.
  const int bid = blockIdx.x;
  const int t = (bid & 7) * 257 + (bid >> 3);
  const unsigned short *A, *W, *bias;
  unsigned short* dst;
  int dstride, Mt, Nt;
  if (t < 2048) {
    if (fp32) { A = c + CINP; W = c + CWKV; bias = c + CBKV; }
    else {
      A = (const unsigned short*)inputs;
      W = (const unsigned short*)Wkv;
      bias = (const unsigned short*)bkv;
    }
    dst = kv; dstride = 1024; Mt = t >> 3; Nt = t & 7;
  } else {
    const int tq = t - 2048;
    if (fp32) { A = c + CQ; W = c + CWQ; bias = c + CBQ; }
    else {
      A = (const unsigned short*)queries;
      W = (const unsigned short*)Wq;
      bias = (const unsigned short*)bq;
    }
    dst = qws; dstride = 512; Mt = tq >> 2; Nt = tq & 3;
  }

  const int tid = threadIdx.x;
  const int w = tid >> 6, l = tid & 63;
  const int quad = l >> 4, l16 = l & 15;
  const int wr = (w >> 1) * 64, wc = (w & 1) * 64;

  // global_load_lds: lane l -> LDS base + l*16B (row lrow=l>>3, granule l&7);
  // source granule pre-swizzled so swizzled ds_read_b128 is conflict-free.
  const int lrow = l >> 3;
  const int gsw = (l & 7) ^ lrow;

  const f32x4 zero4 = {0.f, 0.f, 0.f, 0.f};
  f32x4 acc[4][4];
#pragma unroll
  for (int i = 0; i < 4; ++i)
#pragma unroll
    for (int j = 0; j < 4; ++j) acc[i][j] = zero4;

  const size_t arow0 = (size_t)(Mt * 128) * 512;
  const size_t brow0 = (size_t)(Nt * 128) * 512;

#pragma unroll
  for (int k0 = 0; k0 < 512; k0 += 64) {
    __syncthreads();  // previous compute done; LDS free
#pragma unroll
    for (int k = 0; k < 4; ++k) {
      const int row = w * 32 + k * 8 + lrow;          // 0..127
      const int srcc = k0 + gsw * 8;                  // swizzled source col
      gload_lds16(A + arow0 + (size_t)row * 512 + srcc, Ab + (w * 32 + k * 8) * 64);
      gload_lds16(W + brow0 + (size_t)row * 512 + srcc, Bb + (w * 32 + k * 8) * 64);
    }
    __syncthreads();  // implicit vmcnt(0) drain -> tiles resident
#pragma unroll
    for (int kk2 = 0; kk2 < 2; ++kk2) {
      s16x8 af[4], bfr[4];
#pragma unroll
      for (int i = 0; i < 4; ++i)
        af[i] = *reinterpret_cast<const s16x8*>(stgc(Ab, wr + i * 16 + l16, kk2 * 4 + quad));
#pragma unroll
      for (int j = 0; j < 4; ++j)
        bfr[j] = *reinterpret_cast<const s16x8*>(stgc(Bb, wc + j * 16 + l16, kk2 * 4 + quad));
#pragma unroll
      for (int i = 0; i < 4; ++i)
#pragma unroll
        for (int j = 0; j < 4; ++j) acc[i][j] = mfma16(af[i], bfr[j], acc[i][j]);
    }
  }

  // ---- epilogue: spill C(+bias) into arena (esw swizzle), then coalesced
  //      b128 row stores (16 lanes x 16 B = 256 B per row segment) ----
  __syncthreads();  // all fragment reads done; arena reusable
#pragma unroll
  for (int j = 0; j < 4; ++j) {
    float bb = bf2f(bias[Nt * 128 + wc + j * 16 + l16]);
#pragma unroll
    for (int i = 0; i < 4; ++i)
#pragma unroll
      for (int rg = 0; rg < 4; ++rg) {
        int rl = wr + i * 16 + quad * 4 + rg;  // local row 0..127
        int cl = wc + j * 16 + l16;            // local col 0..127
        arena[esw(rl, cl)] = f2bf(acc[i][j][rg] + bb);
      }
  }
  __syncthreads();
#pragma unroll
  for (int p = 0; p < 8; ++p) {
    int rl = p * 16 + (tid >> 4);   // 0..127
    int c0 = (tid & 15) * 8;        // granule-aligned col
    s16x8 v = *reinterpret_cast<const s16x8*>(&arena[esw(rl, c0)]);
    *reinterpret_cast<s16x8*>(&dst[(size_t)(Mt * 128 + rl) * dstride + Nt * 128 + c0]) = v;
  }
}

// ---------------------------------------------------------------------------
// k_attn: grid (32 stile, 8 b, 2 hpi-pair), 512 thr. Per head-pair: stage
// K-tile [128s][128d] + V^T [128d][128s] from kv, u-GEMM/P/den, num-GEMM.
// LDS exactly 80 KiB -> 2 blocks/CU. T14 named-reg prefetch; u32 V^T staging;
// den via atomicAdd on memset-zeroed den_part. (unchanged from R14)
// ---------------------------------------------------------------------------
template <typename T>
__device__ __forceinline__ void attn_body(const unsigned short* __restrict__ kv,
                                          const unsigned short* __restrict__ qws,
                                          const T* __restrict__ masks,
                                          float* __restrict__ num_part,
                                          float* __restrict__ den_part,
                                          unsigned short* kvb, unsigned short* vtb,
                                          unsigned short* Pb) {
  const int stile = blockIdx.x, b = blockIdx.y;
  const int hp0 = blockIdx.z * 2;  // this block's two head-pairs
  const int s0 = stile * 128;
  const int tid = threadIdx.x;
  const int w = tid >> 6, l = tid & 63;
  const int quad = l >> 4, l16 = l & 15;
  const int hh = w >> 2, mt = (w >> 1) & 1, sh = w & 1, dh = w & 1;
  const int sr2 = tid >> 2, c0 = (tid & 3) * 32;
  const int rp2 = (tid >> 3) * 2;       // 0,2,..,126
  const int cb = (tid & 7) * 16;
  const f32x4 zero4 = {0.f, 0.f, 0.f, 0.f};
  const float scale = 0.044194173824159216f;  // 1/sqrt(512)
  const int bstile = b * 32 + stile;

  const unsigned short* kbase = kv + ((size_t)(b * 4096 + s0 + sr2)) * 1024;
  const unsigned short* vbase0 = kv + ((size_t)(b * 4096 + s0 + rp2)) * 1024 + 512;
  const unsigned short* vbase1 = vbase0 + 1024;

  // prefetch registers (named; loop below fully unrolled)
  s16x8 kp0, kp1, kp2, kp3, va0, va1, vb0, vb1;
  auto loadKV = [&](int hpi) {
    const unsigned short* kr = kbase + hpi * 128 + c0;
    kp0 = *reinterpret_cast<const s16x8*>(kr);
    kp1 = *reinterpret_cast<const s16x8*>(kr + 8);
    kp2 = *reinterpret_cast<const s16x8*>(kr + 16);
    kp3 = *reinterpret_cast<const s16x8*>(kr + 24);
    const unsigned short* v0 = vbase0 + hpi * 128 + cb;
    const unsigned short* v1 = vbase1 + hpi * 128 + cb;
    va0 = *reinterpret_cast<const s16x8*>(v0);
    va1 = *reinterpret_cast<const s16x8*>(v0 + 8);
    vb0 = *reinterpret_cast<const s16x8*>(v1);
    vb1 = *reinterpret_cast<const s16x8*>(v1 + 8);
  };
  loadKV(hp0);

#pragma unroll
  for (int hi = 0; hi < 2; ++hi) {
    const int hpi = hp0 + hi;
    // ---- stage K (swizzled rowmajor, b128 writes) ----
    *reinterpret_cast<s16x8*>(&kvb[sw_idx(sr2, c0)]) = kp0;
    *reinterpret_cast<s16x8*>(&kvb[sw_idx(sr2, c0 + 8)]) = kp1;
    *reinterpret_cast<s16x8*>(&kvb[sw_idx(sr2, c0 + 16)]) = kp2;
    *reinterpret_cast<s16x8*>(&kvb[sw_idx(sr2, c0 + 24)]) = kp3;
    // ---- stage V^T: rows rp2, rp2+1 packed into u32 per transposed elem ----
    // (sw_idx(c, rp2)+1 == sw_idx(c, rp2+1) since rp2 is even: u32-safe)
    {
      union { s16x8 w; unsigned short u[8]; } a0, a1, b0, b1;
      a0.w = va0; a1.w = va1; b0.w = vb0; b1.w = vb1;
#pragma unroll
      for (int e = 0; e < 8; ++e) {
        unsigned int p0 = (unsigned int)a0.u[e] | ((unsigned int)b0.u[e] << 16);
        *reinterpret_cast<unsigned int*>(&vtb[sw_idx(cb + e, rp2)]) = p0;
        unsigned int p1 = (unsigned int)a1.u[e] | ((unsigned int)b1.u[e] << 16);
        *reinterpret_cast<unsigned int*>(&vtb[sw_idx(cb + 8 + e, rp2)]) = p1;
      }
    }
    // ---- T14: issue next head-pair's global loads now ----
    if (hi == 0) loadKV(hpi + 1);
    __syncthreads();

    // ---- u-GEMM + P + den: wave -> (hh, mt, sh) ----
    {
      f32x4 ua[4];
#pragma unroll
      for (int j = 0; j < 4; ++j) ua[j] = zero4;
#pragma unroll
      for (int kk = 0; kk < 2; ++kk) {
        s16x8 aq = *reinterpret_cast<const s16x8*>(
            &qws[((size_t)(b * 32 + mt * 16 + l16)) * 512 + hpi * 128 + hh * 64 + kk * 32 +
                 quad * 8]);
#pragma unroll
        for (int j = 0; j < 4; ++j) {
          s16x8 bk = *reinterpret_cast<const s16x8*>(
              &kvb[sw_idx(sh * 64 + j * 16 + l16, hh * 64 + kk * 32 + quad * 8)]);
          ua[j] = mfma16(aq, bk, ua[j]);
        }
      }
      float dsum[4] = {0.f, 0.f, 0.f, 0.f};
#pragma unroll
      for (int j = 0; j < 4; ++j) {
        int scol = sh * 64 + j * 16 + l16;
        float mask = tofl(masks[(size_t)b * 4096 + s0 + scol]);
#pragma unroll
        for (int rg = 0; rg < 4; ++rg) {
          int qrow = mt * 16 + quad * 4 + rg;
          float uv = ua[j][rg] * scale;
          float e = uv > 0.f ? uv : (__expf(uv) - 1.f);  // elu (low clip dead)
          e = fminf(e, 15.f);
          float p = __expf(e) * mask;
          unsigned short pu = f2bf(p);
          Pb[sw_idx(hh * 32 + qrow, scol)] = pu;
          dsum[rg] += bf2f(pu);  // sum the ROUNDED value num-GEMM uses
        }
      }
      // den: 16-lane shuffle reduce, then atomicAdd (2 waves/location,
      // den_part pre-zeroed by memset) — no LDS needed.
#pragma unroll
      for (int rg = 0; rg < 4; ++rg) {
        float s = dsum[rg];
        s += __shfl_xor(s, 1);
        s += __shfl_xor(s, 2);
        s += __shfl_xor(s, 4);
        s += __shfl_xor(s, 8);
        if (l16 == 0) {
          int qrow = mt * 16 + quad * 4 + rg;
          atomicAdd(&den_part[((size_t)bstile * 32 + qrow) * 8 + hpi * 2 + hh], s);
        }
      }
    }
    __syncthreads();  // Pb complete

    // ---- num-GEMM: wave -> (hh, mt, dh) ----
    {
      f32x4 na0 = zero4, na1 = zero4;
#pragma unroll
      for (int kk = 0; kk < 4; ++kk) {
        s16x8 ap = *reinterpret_cast<const s16x8*>(
            &Pb[sw_idx(hh * 32 + mt * 16 + l16, kk * 32 + quad * 8)]);
        s16x8 bv0 = *reinterpret_cast<const s16x8*>(
            &vtb[sw_idx(hh * 64 + dh * 32 + l16, kk * 32 + quad * 8)]);
        s16x8 bv1 = *reinterpret_cast<const s16x8*>(
            &vtb[sw_idx(hh * 64 + dh * 32 + 16 + l16, kk * 32 + quad * 8)]);
        na0 = mfma16(ap, bv0, na0);
        na1 = mfma16(ap, bv1, na1);
      }
#pragma unroll
      for (int rg = 0; rg < 4; ++rg) {
        int qrow = mt * 16 + quad * 4 + rg;
        size_t base = ((size_t)bstile * 32 + qrow) * 512 + (hpi * 2 + hh) * 64 + dh * 32;
        num_part[base + l16] = na0[rg];
        num_part[base + 16 + l16] = na1[rg];
      }
    }
    __syncthreads();  // before next hi overwrites kvb/vtb/Pb
  }
}

__global__ __launch_bounds__(512, 4) void k_attn(const unsigned short* __restrict__ kv,
                                                 const unsigned short* __restrict__ qws,
                                                 const void* masks,
                                                 float* __restrict__ num_part,
                                                 float* __restrict__ den_part,
                                                 const unsigned short* __restrict__ det) {
  __shared__ unsigned short kvb[128 * 128];  // 32 KiB
  __shared__ unsigned short vtb[128 * 128];  // 32 KiB
  __shared__ unsigned short Pb[64 * 128];    // 16 KiB  -> total exactly 80 KiB
  if (detect_fp32(det))
    attn_body<float>(kv, qws, (const float*)masks, num_part, den_part, kvb, vtb, Pb);
  else
    attn_body<__hip_bfloat16>(kv, qws, (const __hip_bfloat16*)masks, num_part, den_part,
                              kvb, vtb, Pb);
}

// ---------------------------------------------------------------------------
__global__ __launch_bounds__(256) void k_final(const float* __restrict__ num_part,
                                               const float* __restrict__ den_part, void* out,
                                               const unsigned short* __restrict__ det) {
  int i = blockIdx.x * 256 + threadIdx.x;
  int b = i >> 14, qhd = i & 16383;
  int q = (i >> 9) & 31, h = (i >> 6) & 7;
  float sn = 0.f, sd = 0.f;
#pragma unroll 4
  for (int st = 0; st < 32; ++st) {
    sn += num_part[(((size_t)(b * 32 + st)) << 14) + qhd];
    sd += den_part[((size_t)(b * 32 + st) * 32 + q) * 8 + h];
  }
  float v = sn / sd;
  if (detect_fp32(det))
    ((float*)out)[i] = v;
  else
    ((__hip_bfloat16*)out)[i] = __float2bfloat16(v);
}

// ===========================================================================
// FALLBACK PATH (R1-verified, 231 us) — used only if ws is too small.
// ===========================================================================
template <typename T>
__device__ __forceinline__ void qproj_body_fb(const T* __restrict__ queries,
                                              const T* __restrict__ Wq,
                                              const T* __restrict__ bq,
                                              unsigned short* __restrict__ qws,
                                              unsigned short* Abuf, unsigned short* Bbuf) {
  const int Mt = blockIdx.x, Nt = blockIdx.y;
  const int tid = threadIdx.x;
  const int w = tid >> 6, l = tid & 63;
  const int quad = l >> 4, l16 = l & 15;
  const int wr = (w >> 1) * 64, wc = (w & 1) * 64;
  const int r_st = tid >> 1;
  const int kk_st = (tid & 1) * 16;
  const T* Asrc = queries + ((size_t)(Mt * 128 + r_st)) * 512 + kk_st;
  const T* Bsrc = Wq + ((size_t)(Nt * 128 + r_st)) * 512 + kk_st;

  const f32x4 zero4 = {0.f, 0.f, 0.f, 0.f};
  f32x4 acc[4][4];
#pragma unroll
  for (int i = 0; i < 4; ++i)
#pragma unroll
    for (int j = 0; j < 4; ++j) acc[i][j] = zero4;

  RegChunk<T> ra, rb;
  ra.load(Asrc);
  rb.load(Bsrc);
  for (int k0 = 0; k0 < 512; k0 += 32) {
    __syncthreads();
    ra.store(&Abuf[r_st * 32 + kk_st]);
    rb.store(&Bbuf[r_st * 32 + kk_st]);
    if (k0 + 32 < 512) {
      ra.load(Asrc + k0 + 32);
      rb.load(Bsrc + k0 + 32);
    }
    __syncthreads();
    s16x8 af[4], bfr[4];
#pragma unroll
    for (int i = 0; i < 4; ++i)
      af[i] = *reinterpret_cast<const s16x8*>(&Abuf[(wr + i * 16 + l16) * 32 + quad * 8]);
#pragma unroll
    for (int j = 0; j < 4; ++j)
      bfr[j] = *reinterpret_cast<const s16x8*>(&Bbuf[(wc + j * 16 + l16) * 32 + quad * 8]);
#pragma unroll
    for (int i = 0; i < 4; ++i)
#pragma unroll
      for (int j = 0; j < 4; ++j) acc[i][j] = mfma16(af[i], bfr[j], acc[i][j]);
  }
#pragma unroll
  for (int j = 0; j < 4; ++j) {
    float bb = tofl(bq[Nt * 128 + wc + j * 16 + l16]);
#pragma unroll
    for (int i = 0; i < 4; ++i)
#pragma unroll
      for (int rg = 0; rg < 4; ++rg) {
        int row = Mt * 128 + wr + i * 16 + quad * 4 + rg;
        int col = Nt * 128 + wc + j * 16 + l16;
        qws[(size_t)row * 512 + col] = f2bf(acc[i][j][rg] + bb);
      }
  }
}

__global__ __launch_bounds__(256) void k_qproj_fb(const void* queries, const void* Wq,
                                                  const void* bq, unsigned short* qws,
                                                  const unsigned short* __restrict__ det) {
  __shared__ unsigned short Abuf[128 * 32];
  __shared__ unsigned short Bbuf[128 * 32];
  if (detect_fp32(det))
    qproj_body_fb<float>((const float*)queries, (const float*)Wq, (const float*)bq, qws,
                         Abuf, Bbuf);
  else
    qproj_body_fb<__hip_bfloat16>((const __hip_bfloat16*)queries,
                                  (const __hip_bfloat16*)Wq, (const __hip_bfloat16*)bq, qws,
                                  Abuf, Bbuf);
}

template <typename T>
__device__ __forceinline__ void fused_body_fb(
    const T* __restrict__ inputs, const T* __restrict__ masks, const T* __restrict__ Wkv,
    const T* __restrict__ bkv, const unsigned short* __restrict__ qws,
    float* __restrict__ num, float* __restrict__ den, unsigned short* Abuf,
    unsigned short* Bbuf, unsigned short* kvbuf, unsigned short* vbuf,
    unsigned short* Pbuf) {
  const int stile = blockIdx.x;
  const int b = blockIdx.y;
  const int hp = blockIdx.z;
  const int s0 = stile * 128;
  const int tid = threadIdx.x;
  const int w = tid >> 6;
  const int l = tid & 63;
  const int quad = l >> 4;
  const int l16 = l & 15;
  const int which = w >> 2;
  const int wr = ((w >> 1) & 1) * 64;
  const int wc = (w & 1) * 64;

  const f32x4 zero4 = {0.f, 0.f, 0.f, 0.f};
  f32x4 acc[4][4];
#pragma unroll
  for (int i = 0; i < 4; ++i)
#pragma unroll
    for (int j = 0; j < 4; ++j) acc[i][j] = zero4;

  const int sr = tid >> 2;
  const int sc = tid & 3;
  const T* Asrc = inputs + ((size_t)(b * 4096 + s0 + sr)) * 512 + sc * 16;
  const T* BKs = Wkv + ((size_t)(hp * 128 + sr)) * 512 + sc * 16;
  const T* BVs = Wkv + ((size_t)(512 + hp * 128 + sr)) * 512 + sc * 16;
  unsigned short* ad0 = stg(Abuf, sr, sc * 2);
  unsigned short* ad1 = stg(Abuf, sr, sc * 2 + 1);
  unsigned short* bk0 = stg(Bbuf, sr, sc * 2);
  unsigned short* bk1 = stg(Bbuf, sr, sc * 2 + 1);
  unsigned short* bv0 = stg(Bbuf, 128 + sr, sc * 2);
  unsigned short* bv1 = stg(Bbuf, 128 + sr, sc * 2 + 1);

  RegChunk<T> ra0, ra1, rbk, rbv;
  ra0.load(Asrc);
  ra1.load(Asrc + 64);
  rbk.load(BKs);
  rbv.load(BVs);

#pragma unroll
  for (int it2 = 0; it2 < 4; ++it2) {
#pragma unroll
    for (int ph = 0; ph < 2; ++ph) {
      const int it = it2 * 2 + ph;
      RegChunk<T>& ra = ph ? ra1 : ra0;
      __syncthreads();
      ra.store2(ad0, ad1);
      rbk.store2(bk0, bk1);
      rbv.store2(bv0, bv1);
      if (it < 6) ra.load(Asrc + (it + 2) * 64);
      if (it < 7) {
        rbk.load(BKs + (it + 1) * 64);
        rbv.load(BVs + (it + 1) * 64);
      }
      __syncthreads();
#pragma unroll
      for (int kk2 = 0; kk2 < 2; ++kk2) {
        s16x8 af[4], bfr[4];
#pragma unroll
        for (int i = 0; i < 4; ++i)
          af[i] = *reinterpret_cast<const s16x8*>(stgc(Abuf, wr + i * 16 + l16, kk2 * 4 + quad));
#pragma unroll
        for (int j = 0; j < 4; ++j)
          bfr[j] = *reinterpret_cast<const s16x8*>(
              stgc(Bbuf, which * 128 + wc + j * 16 + l16, kk2 * 4 + quad));
#pragma unroll
        for (int i = 0; i < 4; ++i)
#pragma unroll
          for (int j = 0; j < 4; ++j) acc[i][j] = mfma16(af[i], bfr[j], acc[i][j]);
      }
    }
  }

#pragma unroll
  for (int j = 0; j < 4; ++j) {
    float bb = tofl(bkv[which * 512 + hp * 128 + wc + j * 16 + l16]);
#pragma unroll
    for (int i = 0; i < 4; ++i)
#pragma unroll
      for (int rg = 0; rg < 4; ++rg) {
        int sl = wr + i * 16 + quad * 4 + rg;
        int c = wc + j * 16 + l16;
        unsigned short bv = f2bf(acc[i][j][rg] + bb);
        if (which == 0)
          kvbuf[sw_idx(sl, c)] = bv;
        else
          vbuf[sw_idx(c, sl)] = bv;
      }
  }
  __syncthreads();

  const int hh = w >> 2, mt = (w >> 1) & 1, sh = w & 1;
  {
    f32x4 ua[4];
#pragma unroll
    for (int j = 0; j < 4; ++j) ua[j] = zero4;
#pragma unroll
    for (int kk = 0; kk < 2; ++kk) {
      s16x8 aq = *reinterpret_cast<const s16x8*>(
          qws + ((size_t)(b * 32 + mt * 16 + l16)) * 512 + hp * 128 + hh * 64 + kk * 32 +
          quad * 8);
#pragma unroll
      for (int j = 0; j < 4; ++j) {
        s16x8 bk = *reinterpret_cast<const s16x8*>(
            &kvbuf[sw_idx(sh * 64 + j * 16 + l16, hh * 64 + kk * 32 + quad * 8)]);
        ua[j] = mfma16(aq, bk, ua[j]);
      }
    }
    const float scale = 0.044194173824159216f;
    float dsum[4] = {0.f, 0.f, 0.f, 0.f};
#pragma unroll
    for (int j = 0; j < 4; ++j) {
      int scol = sh * 64 + j * 16 + l16;
      float mask = tofl(masks[(size_t)b * 4096 + s0 + scol]);
#pragma unroll
      for (int rg = 0; rg < 4; ++rg) {
        int qrow = mt * 16 + quad * 4 + rg;
        float uv = ua[j][rg] * scale;
        float e = uv > 0.f ? uv : (__expf(uv) - 1.f);
        e = fminf(e, 15.f);
        float p = __expf(e) * mask;
        unsigned short pu = f2bf(p);
        Pbuf[sw_idx(hh * 32 + qrow, scol)] = pu;
        dsum[rg] += bf2f(pu);
      }
    }
#pragma unroll
    for (int rg = 0; rg < 4; ++rg) {
      float s = dsum[rg];
      s += __shfl_xor(s, 1);
      s += __shfl_xor(s, 2);
      s += __shfl_xor(s, 4);
      s += __shfl_xor(s, 8);
      if (l16 == 0) {
        int qrow = mt * 16 + quad * 4 + rg;
        atomicAdd(&den[((size_t)(b * 32 + qrow)) * 8 + hp * 2 + hh], s);
      }
    }
  }
  __syncthreads();

  {
    const int dh = w & 1;
    f32x4 na[2];
    na[0] = zero4;
    na[1] = zero4;
#pragma unroll
    for (int kk = 0; kk < 4; ++kk) {
      s16x8 ap = *reinterpret_cast<const s16x8*>(
          &Pbuf[sw_idx(hh * 32 + mt * 16 + l16, kk * 32 + quad * 8)]);
#pragma unroll
      for (int jj = 0; jj < 2; ++jj) {
        int j = dh * 2 + jj;
        s16x8 bv = *reinterpret_cast<const s16x8*>(
            &vbuf[sw_idx(hh * 64 + j * 16 + l16, kk * 32 + quad * 8)]);
        na[jj] = mfma16(ap, bv, na[jj]);
      }
    }
    const int h = hp * 2 + hh;
#pragma unroll
    for (int jj = 0; jj < 2; ++jj) {
      int d = (dh * 2 + jj) * 16 + l16;
#pragma unroll
      for (int rg = 0; rg < 4; ++rg) {
        int qrow = mt * 16 + quad * 4 + rg;
        atomicAdd(&num[(((size_t)(b * 32 + qrow)) * 8 + h) * 64 + d], na[jj][rg]);
      }
    }
  }
}

__global__ __launch_bounds__(512, 2) void k_fused_fb(const void* inputs, const void* masks,
                                                     const void* Wkv, const void* bkv,
                                                     const unsigned short* __restrict__ qws,
                                                     float* __restrict__ num,
                                                     float* __restrict__ den) {
  __shared__ unsigned short Abuf[128 * 64];
  __shared__ unsigned short Bbuf[256 * 64];
  __shared__ unsigned short kvbuf[128 * 128];
  __shared__ unsigned short vbuf[128 * 128];
  __shared__ unsigned short Pbuf[64 * 128];
  if (detect_fp32((const unsigned short*)inputs))
    fused_body_fb<float>((const float*)inputs, (const float*)masks, (const float*)Wkv,
                         (const float*)bkv, qws, num, den, Abuf, Bbuf, kvbuf, vbuf, Pbuf);
  else
    fused_body_fb<__hip_bfloat16>((const __hip_bfloat16*)inputs,
                                  (const __hip_bfloat16*)masks, (const __hip_bfloat16*)Wkv,
                                  (const __hip_bfloat16*)bkv, qws, num, den, Abuf, Bbuf,
                                  kvbuf, vbuf, Pbuf);
}

__global__ __launch_bounds__(256) void k_div_fb(const float* __restrict__ num,
                                                const float* __restrict__ den, void* out,
                                                const unsigned short* __restrict__ det) {
  int i = blockIdx.x * 256 + threadIdx.x;
  float v = num[i] / den[i >> 6];
  if (detect_fp32(det))
    ((float*)out)[i] = v;
  else
    ((__hip_bfloat16*)out)[i] = __float2bfloat16(v);
}

// ---------------------------------------------------------------------------
extern "C" void kernel_launch(void* const* d_in, const int* in_sizes, int n_in,
                              void* d_out, int out_size, void* d_ws, size_t ws_size,
                              hipStream_t stream) {
  // d_in: 0 inputs, 1 queries, 2 masks, 3 Wkv, 4 bkv, 5 Wq, 6 bq
  char* ws = (char*)d_ws;
  if (ws_size >= 119802880) {
    // NEW path. ws (bytes):
    //   [0]         conv region (bf16, fp32 case only; 35,392,512 B)
    //   [35392512]  kv  bf16 [32768][1024]  (67,108,864 B)
    //   [102501376] qws bf16 [256][512]     (262,144 B)
    //   [102763520] num_part f32            (16,777,216 B)
    //   [119540736] den_part f32            (262,144 B)
    unsigned short* conv = (unsigned short*)ws;
    unsigned short* kv = (unsigned short*)(ws + 35392512);
    unsigned short* qws = (unsigned short*)(ws + 102501376);
    float* num_part = (float*)(ws + 102763520);
    float* den_part = (float*)(ws + 119540736);

    hipMemsetAsync(den_part, 0, 262144, stream);  // den accumulated via atomics
    k_conv<<<2120, 256, 0, stream>>>(d_in[0], d_in[1], d_in[3], d_in[5], d_in[4], d_in[6],
                                     conv);
    k_gemm2<<<2056, 256, 0, stream>>>(conv, d_in[0], d_in[1], d_in[3], d_in[5], d_in[4],
                                      d_in[6], kv, qws);
    k_attn<<<dim3(32, 8, 2), 512, 0, stream>>>(kv, qws, d_in[2], num_part, den_part,
                                               (const unsigned short*)d_in[0]);
    k_final<<<512, 256, 0, stream>>>(num_part, den_part, d_out,
                                     (const unsigned short*)d_in[0]);
  } else if (ws_size >= 802816) {
    // FALLBACK (R1 path). ws: [1024] den ; [16384] num ; [540672] qws
    float* den = (float*)(ws + 1024);
    float* num = (float*)(ws + 16384);
    unsigned short* qws = (unsigned short*)(ws + 540672);

    hipMemsetAsync(d_ws, 0, 540672, stream);
    dim3 gq(2, 4);
    k_qproj_fb<<<gq, 256, 0, stream>>>(d_in[1], d_in[5], d_in[6], qws,
                                       (const unsigned short*)d_in[0]);
    dim3 g2(32, 8, 4);
    k_fused_fb<<<g2, 512, 0, stream>>>(d_in[0], d_in[2], d_in[3], d_in[4], qws, num, den);
    k_div_fb<<<512, 256, 0, stream>>>(num, den, d_out, (const unsigned short*)d_in[0]);
  }
}

// Round 13
// 172.785 us; speedup vs baseline: 1.0928x; 1.0638x over previous
//
#include <hip/hip_runtime.h>
#include <hip/hip_bf16.h>

// ---------------------------------------------------------------------------
// MultiHeadAttention for MI355X (gfx950)
// B=8 S=4096 Q=32 H=8 D=64 IN=512 NKV=1024
// R17: resubmission of R16 (prior bench died on container acquisition, not
//      kernel). FUSED projection+attention (kills the 131 MB kv round-trip).
//   k_conv  : fp32 -> bf16 conv region; bf16 -> no-op (zero-copy).
//   k_qp    : 8-block 128x128 gload_lds GEMM (verified gemm2 tile) -> qws.
//   k_fused2: grid 1024 x 512 thr. Per block: gload_lds K-loop stages
//             {A 128x64, Wk 128x64, Wv 128x64}; waves 0-3 accumulate the
//             K-tile, 4-7 the V-tile (R1-verified decomposition); spill into
//             aliased 80 KiB arena (kvb/vtb/Pb); then R14-verified attention
//             phase -> per-block partials. 2 blocks/CU.
//   k_final : reduce partials + divide.
// Fallback: R1-verified 3-kernel path if ws_size < 120 MB.
// ---------------------------------------------------------------------------

typedef float f32x4 __attribute__((ext_vector_type(4)));
typedef short s16x8 __attribute__((ext_vector_type(8)));

__device__ __forceinline__ unsigned short f2bf(float f) {
  union { __hip_bfloat16 h; unsigned short u; } cv;
  cv.h = __float2bfloat16(f);
  return cv.u;
}
__device__ __forceinline__ float bf2f(unsigned short u) {
  union { unsigned short u; __hip_bfloat16 h; } cv;
  cv.u = u;
  return __bfloat162float(cv.h);
}
__device__ __forceinline__ float tofl(float v) { return v; }
__device__ __forceinline__ float tofl(__hip_bfloat16 v) { return __bfloat162float(v); }

__device__ __forceinline__ f32x4 mfma16(s16x8 a, s16x8 b, f32x4 c) {
  return __builtin_amdgcn_mfma_f32_16x16x32_bf16(a, b, c, 0, 0, 0);
}

// dtype detection (1 = fp32, 0 = bf16)
__device__ __forceinline__ int detect_fp32(const unsigned short* __restrict__ in16) {
  unsigned short v = in16[2 * (threadIdx.x & 63)];
  int e = (v >> 7) & 0xFF;
  unsigned long long m = __ballot(e >= 100 && e <= 130);
  return __popcll(m) < 48 ? 1 : 0;
}

// direct global->LDS 16B (per-lane gptr, wave-uniform LDS base; HW scatters
// lane i -> base + i*16B)
__device__ __forceinline__ void gload_lds16(const void* g, void* s) {
  __builtin_amdgcn_global_load_lds(
      (const __attribute__((address_space(1))) unsigned int*)(g),
      (__attribute__((address_space(3))) unsigned int*)(s), 16, 0, 0);
}

// ---------------------------------------------------------------------------
// LDS swizzles (16B-granule XOR over 8-granule (128 B) rows)
// ---------------------------------------------------------------------------
__device__ __forceinline__ unsigned short* stg(unsigned short* buf, int r, int u) {
  return buf + r * 64 + ((u ^ (r & 7)) << 3);
}
__device__ __forceinline__ const unsigned short* stgc(const unsigned short* buf, int r, int u) {
  return buf + r * 64 + ((u ^ (r & 7)) << 3);
}
__device__ __forceinline__ int sw_idx(int r, int c) {
  return r * 128 + ((((c >> 3) ^ (r & 7)) << 3) | (c & 7));
}

// 8-element bf16 fragment load from global (with fp32->bf16 convert)
template <typename T>
__device__ __forceinline__ s16x8 load_frag8(const T* p);
template <>
__device__ __forceinline__ s16x8 load_frag8<float>(const float* p) {
  const float4* q = reinterpret_cast<const float4*>(p);
  float4 a = q[0], b = q[1];
  union { unsigned short u[8]; s16x8 w; } t;
  t.u[0] = f2bf(a.x); t.u[1] = f2bf(a.y); t.u[2] = f2bf(a.z); t.u[3] = f2bf(a.w);
  t.u[4] = f2bf(b.x); t.u[5] = f2bf(b.y); t.u[6] = f2bf(b.z); t.u[7] = f2bf(b.w);
  return t.w;
}
template <>
__device__ __forceinline__ s16x8 load_frag8<__hip_bfloat16>(const __hip_bfloat16* p) {
  return *reinterpret_cast<const s16x8*>(p);
}

// 16-element (along K) register chunk, for the fallback path
template <typename T> struct RegChunk;
template <> struct RegChunk<float> {
  float4 v[4];
  __device__ __forceinline__ void load(const float* p) {
    const float4* q = reinterpret_cast<const float4*>(p);
    v[0] = q[0]; v[1] = q[1]; v[2] = q[2]; v[3] = q[3];
  }
  __device__ __forceinline__ void store(unsigned short* d) {
    union { unsigned short u[16]; s16x8 w[2]; } t;
    const float* f = reinterpret_cast<const float*>(v);
#pragma unroll
    for (int i = 0; i < 16; ++i) t.u[i] = f2bf(f[i]);
    reinterpret_cast<s16x8*>(d)[0] = t.w[0];
    reinterpret_cast<s16x8*>(d)[1] = t.w[1];
  }
  __device__ __forceinline__ void store2(unsigned short* d0, unsigned short* d1) {
    union { unsigned short u[16]; s16x8 w[2]; } t;
    const float* f = reinterpret_cast<const float*>(v);
#pragma unroll
    for (int i = 0; i < 16; ++i) t.u[i] = f2bf(f[i]);
    *reinterpret_cast<s16x8*>(d0) = t.w[0];
    *reinterpret_cast<s16x8*>(d1) = t.w[1];
  }
};
template <> struct RegChunk<__hip_bfloat16> {
  s16x8 v[2];
  __device__ __forceinline__ void load(const __hip_bfloat16* p) {
    const s16x8* q = reinterpret_cast<const s16x8*>(p);
    v[0] = q[0]; v[1] = q[1];
  }
  __device__ __forceinline__ void store(unsigned short* d) {
    reinterpret_cast<s16x8*>(d)[0] = v[0];
    reinterpret_cast<s16x8*>(d)[1] = v[1];
  }
  __device__ __forceinline__ void store2(unsigned short* d0, unsigned short* d1) {
    *reinterpret_cast<s16x8*>(d0) = v[0];
    *reinterpret_cast<s16x8*>(d1) = v[1];
  }
};

// ===========================================================================
// NEW PATH
// ===========================================================================

// conv region element offsets (bf16 elems) — used ONLY in the fp32 case
#define CINP 0
#define CQ   16777216
#define CWKV 16908288
#define CWQ  17432576
#define CBKV 17694720
#define CBQ  17695744
#define CTOT 17696256

// ---------------------------------------------------------------------------
// k_conv: fp32 case -> convert everything to bf16 into ws. bf16 case -> no-op
// (downstream kernels read the original buffers directly).
// ---------------------------------------------------------------------------
__global__ __launch_bounds__(256) void k_conv(const void* inputs, const void* queries,
                                              const void* Wkv, const void* Wq,
                                              const void* bkv, const void* bq,
                                              unsigned short* __restrict__ dst) {
  const int fp32 = detect_fp32((const unsigned short*)inputs);
  if (!fp32) return;  // zero-copy: originals are already bf16
  const int bid = blockIdx.x, tid = threadIdx.x;
  if (bid < 2048) {
    // inputs: 2,097,152 units = 2048 blocks x 1024 units, 4/thread
    size_t u = (size_t)bid * 1024 + tid;
#pragma unroll
    for (int k = 0; k < 4; ++k, u += 256) {
      size_t e = u * 8;
      s16x8 v = load_frag8<float>((const float*)inputs + e);
      *reinterpret_cast<s16x8*>(dst + e) = v;
    }
  } else {
    // tail: 114,880 units over 72 blocks
    size_t i8 = (size_t)(bid - 2048) * 256 + tid;
    for (; i8 < 114880; i8 += (size_t)72 * 256) {
      size_t e = CQ + i8 * 8;
      const void* src;
      size_t off;
      if (e < CWKV) { src = queries; off = e - CQ; }
      else if (e < CWQ) { src = Wkv; off = e - CWKV; }
      else if (e < CBKV) { src = Wq; off = e - CWQ; }
      else if (e < CBQ) { src = bkv; off = e - CBKV; }
      else { src = bq; off = e - CBQ; }
      s16x8 v = load_frag8<float>((const float*)src + off);
      *reinterpret_cast<s16x8*>(dst + e) = v;
    }
  }
}

// ---------------------------------------------------------------------------
// k_qp: qws[256][512] = queries @ Wq^T + bq. 8 blocks x 256 thr, the
// VERIFIED gemm2 128x128 gload_lds tile (single-buffered, 0 bank conflicts,
// R14 direct-store epilogue).
// MFMA 16x16x32_bf16 layouts (HW-verified):
//   A: m=lane&15, k=quad*8+j ; B: n=lane&15, k=quad*8+j ;
//   D: col=lane&15, row=quad*4+reg
// ---------------------------------------------------------------------------
__global__ __launch_bounds__(256) void k_qp(const unsigned short* __restrict__ c,
                                            const void* inputs, const void* queries,
                                            const void* Wq, const void* bq,
                                            unsigned short* __restrict__ qws) {
  __shared__ unsigned short Ab[128 * 64];  // 16 KiB
  __shared__ unsigned short Bb[128 * 64];  // 16 KiB

  const int fp32 = detect_fp32((const unsigned short*)inputs);
  const unsigned short *A, *W, *bias;
  if (fp32) { A = c + CQ; W = c + CWQ; bias = c + CBQ; }
  else {
    A = (const unsigned short*)queries;
    W = (const unsigned short*)Wq;
    bias = (const unsigned short*)bq;
  }
  const int t = blockIdx.x;  // 0..7
  const int Mt = t >> 2, Nt = t & 3;

  const int tid = threadIdx.x;
  const int w = tid >> 6, l = tid & 63;
  const int quad = l >> 4, l16 = l & 15;
  const int wr = (w >> 1) * 64, wc = (w & 1) * 64;
  const int lrow = l >> 3;
  const int gsw = (l & 7) ^ lrow;

  const f32x4 zero4 = {0.f, 0.f, 0.f, 0.f};
  f32x4 acc[4][4];
#pragma unroll
  for (int i = 0; i < 4; ++i)
#pragma unroll
    for (int j = 0; j < 4; ++j) acc[i][j] = zero4;

  const size_t arow0 = (size_t)(Mt * 128) * 512;
  const size_t brow0 = (size_t)(Nt * 128) * 512;

#pragma unroll
  for (int k0 = 0; k0 < 512; k0 += 64) {
    __syncthreads();
#pragma unroll
    for (int k = 0; k < 4; ++k) {
      const int row = w * 32 + k * 8 + lrow;
      const int srcc = k0 + gsw * 8;
      gload_lds16(A + arow0 + (size_t)row * 512 + srcc, Ab + (w * 32 + k * 8) * 64);
      gload_lds16(W + brow0 + (size_t)row * 512 + srcc, Bb + (w * 32 + k * 8) * 64);
    }
    __syncthreads();
#pragma unroll
    for (int kk2 = 0; kk2 < 2; ++kk2) {
      s16x8 af[4], bfr[4];
#pragma unroll
      for (int i = 0; i < 4; ++i)
        af[i] = *reinterpret_cast<const s16x8*>(stgc(Ab, wr + i * 16 + l16, kk2 * 4 + quad));
#pragma unroll
      for (int j = 0; j < 4; ++j)
        bfr[j] = *reinterpret_cast<const s16x8*>(stgc(Bb, wc + j * 16 + l16, kk2 * 4 + quad));
#pragma unroll
      for (int i = 0; i < 4; ++i)
#pragma unroll
        for (int j = 0; j < 4; ++j) acc[i][j] = mfma16(af[i], bfr[j], acc[i][j]);
    }
  }

#pragma unroll
  for (int j = 0; j < 4; ++j) {
    float bb = bf2f(bias[Nt * 128 + wc + j * 16 + l16]);
#pragma unroll
    for (int i = 0; i < 4; ++i)
#pragma unroll
      for (int rg = 0; rg < 4; ++rg) {
        int row = Mt * 128 + wr + i * 16 + quad * 4 + rg;
        int col = Nt * 128 + wc + j * 16 + l16;
        qws[(size_t)row * 512 + col] = f2bf(acc[i][j][rg] + bb);
      }
  }
}

// ---------------------------------------------------------------------------
// k_fused2: fused KV-projection + attention. 1024 blocks x 512 thr.
// Remap (R6-verified bijection): 4 hp-blocks of one (b,stile) share an XCD
// in one dispatch window -> A-tile L2 reuse.
// K-loop: stage A/Wk/Wv via gload_lds (linear dest, pre-swizzled source);
// waves 0-3 accumulate K-quadrants, 4-7 V-quadrants. Spill into aliased
// arena (kvb [s][d], vtb [d][s], both sw_idx-swizzled). Then the R14
// attention phase: u-GEMM -> P/den -> num-GEMM -> partials.
// ---------------------------------------------------------------------------
__global__ __launch_bounds__(512, 4) void k_fused2(
    const unsigned short* __restrict__ c, const void* inputs, const void* masks_,
    const void* Wkv, const void* bkv, const unsigned short* __restrict__ qws,
    float* __restrict__ num_part, float* __restrict__ den_part) {
  __shared__ unsigned short arena[40960];  // 80 KiB
  unsigned short* Ab = arena;              // [128][64] (K-loop)
  unsigned short* Wk = arena + 8192;       // [128][64]
  unsigned short* Wv = arena + 16384;      // [128][64]
  unsigned short* kvb = arena;             // [128][128] (attn, aliases)
  unsigned short* vtb = arena + 16384;     // [128][128]
  unsigned short* Pb = arena + 32768;      // [64][128]

  const int fp32 = detect_fp32((const unsigned short*)inputs);

  // grid remap: x -> (stile, b, hp); 4 hp-blocks of one (b,stile) have the
  // same x%8 (same XCD) within a 32-index window.
  const int x = blockIdx.x;
  const int hp = (x >> 3) & 3;
  const int g = (x & 7) + (x >> 5) * 8;  // 0..255
  const int stile = g & 31, b = g >> 5;
  const int s0 = stile * 128;

  const unsigned short *A, *Wkv16, *bkv16;
  if (fp32) { A = c + CINP; Wkv16 = c + CWKV; bkv16 = c + CBKV; }
  else {
    A = (const unsigned short*)inputs;
    Wkv16 = (const unsigned short*)Wkv;
    bkv16 = (const unsigned short*)bkv;
  }

  const int tid = threadIdx.x;
  const int w = tid >> 6, l = tid & 63;
  const int quad = l >> 4, l16 = l & 15;
  const int which = w >> 2;            // 0 = K waves, 1 = V waves
  const int wq = w & 3;
  const int wr = (wq >> 1) * 64, wc = (wq & 1) * 64;
  const int lrow = l >> 3;
  const int gsw = (l & 7) ^ lrow;

  const f32x4 zero4 = {0.f, 0.f, 0.f, 0.f};
  f32x4 acc[4][4];
#pragma unroll
  for (int i = 0; i < 4; ++i)
#pragma unroll
    for (int j = 0; j < 4; ++j) acc[i][j] = zero4;

  const size_t arow0 = (size_t)(b * 4096 + s0) * 512;
  const size_t krow0 = (size_t)(hp * 128) * 512;
  const size_t vrow0 = (size_t)(512 + hp * 128) * 512;

  // ---- K-loop: 8 steps of BK=64; 6 gload_lds per wave per step ----
#pragma unroll
  for (int k0 = 0; k0 < 512; k0 += 64) {
    __syncthreads();  // previous compute done; staging free
#pragma unroll
    for (int k = 0; k < 2; ++k) {
      const int rbase = w * 16 + k * 8;   // 0..120 (8-row chunk base)
      const int srcc = k0 + gsw * 8;      // pre-swizzled source col
      gload_lds16(A + arow0 + (size_t)(rbase + lrow) * 512 + srcc, Ab + rbase * 64);
      gload_lds16(Wkv16 + krow0 + (size_t)(rbase + lrow) * 512 + srcc, Wk + rbase * 64);
      gload_lds16(Wkv16 + vrow0 + (size_t)(rbase + lrow) * 512 + srcc, Wv + rbase * 64);
    }
    __syncthreads();  // implicit vmcnt(0): tiles resident
    const unsigned short* Wsel = which ? Wv : Wk;
#pragma unroll
    for (int kk2 = 0; kk2 < 2; ++kk2) {
      s16x8 af[4], bfr[4];
#pragma unroll
      for (int i = 0; i < 4; ++i)
        af[i] = *reinterpret_cast<const s16x8*>(stgc(Ab, wr + i * 16 + l16, kk2 * 4 + quad));
#pragma unroll
      for (int j = 0; j < 4; ++j)
        bfr[j] = *reinterpret_cast<const s16x8*>(stgc(Wsel, wc + j * 16 + l16, kk2 * 4 + quad));
#pragma unroll
      for (int i = 0; i < 4; ++i)
#pragma unroll
        for (int j = 0; j < 4; ++j) acc[i][j] = mfma16(af[i], bfr[j], acc[i][j]);
    }
  }

  // ---- spill acc(+bias): K -> kvb [s][d], V -> vtb [d][s] (R1-verified) ----
  __syncthreads();  // all staging reads done; arena reusable
#pragma unroll
  for (int j = 0; j < 4; ++j) {
    float bb = bf2f(bkv16[which * 512 + hp * 128 + wc + j * 16 + l16]);
#pragma unroll
    for (int i = 0; i < 4; ++i)
#pragma unroll
      for (int rg = 0; rg < 4; ++rg) {
        int sl = wr + i * 16 + quad * 4 + rg;  // s-row (local)
        int cc = wc + j * 16 + l16;            // d-col (local)
        unsigned short bv = f2bf(acc[i][j][rg] + bb);
        if (which == 0) kvb[sw_idx(sl, cc)] = bv;
        else vtb[sw_idx(cc, sl)] = bv;
      }
  }
  __syncthreads();  // kvb/vtb complete

  // ================= attention phase (R14-verified math) =================
  const int hh = which, mt = (w >> 1) & 1, sh = w & 1, dh = w & 1;
  const float scale = 0.044194173824159216f;  // 1/sqrt(512)
  const int bstile = b * 32 + stile;

  // ---- u-GEMM + P + den ----
  {
    f32x4 ua[4];
#pragma unroll
    for (int j = 0; j < 4; ++j) ua[j] = zero4;
#pragma unroll
    for (int kk = 0; kk < 2; ++kk) {
      s16x8 aq = *reinterpret_cast<const s16x8*>(
          &qws[((size_t)(b * 32 + mt * 16 + l16)) * 512 + hp * 128 + hh * 64 + kk * 32 +
               quad * 8]);
#pragma unroll
      for (int j = 0; j < 4; ++j) {
        s16x8 bk = *reinterpret_cast<const s16x8*>(
            &kvb[sw_idx(sh * 64 + j * 16 + l16, hh * 64 + kk * 32 + quad * 8)]);
        ua[j] = mfma16(aq, bk, ua[j]);
      }
    }
    float dsum[4] = {0.f, 0.f, 0.f, 0.f};
#pragma unroll
    for (int j = 0; j < 4; ++j) {
      int scol = sh * 64 + j * 16 + l16;
      size_t midx = (size_t)b * 4096 + s0 + scol;
      float mask = fp32 ? ((const float*)masks_)[midx]
                        : bf2f(((const unsigned short*)masks_)[midx]);
#pragma unroll
      for (int rg = 0; rg < 4; ++rg) {
        int qrow = mt * 16 + quad * 4 + rg;
        float uv = ua[j][rg] * scale;
        float e = uv > 0.f ? uv : (__expf(uv) - 1.f);  // elu (low clip dead)
        e = fminf(e, 15.f);
        float p = __expf(e) * mask;
        unsigned short pu = f2bf(p);
        Pb[sw_idx(hh * 32 + qrow, scol)] = pu;
        dsum[rg] += bf2f(pu);  // sum the ROUNDED value num-GEMM uses
      }
    }
    // den: 16-lane shuffle reduce; the two s-half waves atomicAdd (den_part
    // pre-zeroed by memset).
#pragma unroll
    for (int rg = 0; rg < 4; ++rg) {
      float s = dsum[rg];
      s += __shfl_xor(s, 1);
      s += __shfl_xor(s, 2);
      s += __shfl_xor(s, 4);
      s += __shfl_xor(s, 8);
      if (l16 == 0) {
        int qrow = mt * 16 + quad * 4 + rg;
        atomicAdd(&den_part[((size_t)bstile * 32 + qrow) * 8 + hp * 2 + hh], s);
      }
    }
  }
  __syncthreads();  // Pb complete

  // ---- num-GEMM -> num_part (disjoint per (hp,hh,mt,dh): no atomics) ----
  {
    f32x4 na0 = zero4, na1 = zero4;
#pragma unroll
    for (int kk = 0; kk < 4; ++kk) {
      s16x8 ap = *reinterpret_cast<const s16x8*>(
          &Pb[sw_idx(hh * 32 + mt * 16 + l16, kk * 32 + quad * 8)]);
      s16x8 bv0 = *reinterpret_cast<const s16x8*>(
          &vtb[sw_idx(hh * 64 + dh * 32 + l16, kk * 32 + quad * 8)]);
      s16x8 bv1 = *reinterpret_cast<const s16x8*>(
          &vtb[sw_idx(hh * 64 + dh * 32 + 16 + l16, kk * 32 + quad * 8)]);
      na0 = mfma16(ap, bv0, na0);
      na1 = mfma16(ap, bv1, na1);
    }
#pragma unroll
    for (int rg = 0; rg < 4; ++rg) {
      int qrow = mt * 16 + quad * 4 + rg;
      size_t base = ((size_t)bstile * 32 + qrow) * 512 + (hp * 2 + hh) * 64 + dh * 32;
      num_part[base + l16] = na0[rg];
      num_part[base + 16 + l16] = na1[rg];
    }
  }
}

// ---------------------------------------------------------------------------
__global__ __launch_bounds__(256) void k_final(const float* __restrict__ num_part,
                                               const float* __restrict__ den_part, void* out,
                                               const unsigned short* __restrict__ det) {
  int i = blockIdx.x * 256 + threadIdx.x;
  int b = i >> 14, qhd = i & 16383;
  int q = (i >> 9) & 31, h = (i >> 6) & 7;
  float sn = 0.f, sd = 0.f;
#pragma unroll 4
  for (int st = 0; st < 32; ++st) {
    sn += num_part[(((size_t)(b * 32 + st)) << 14) + qhd];
    sd += den_part[((size_t)(b * 32 + st) * 32 + q) * 8 + h];
  }
  float v = sn / sd;
  if (detect_fp32(det))
    ((float*)out)[i] = v;
  else
    ((__hip_bfloat16*)out)[i] = __float2bfloat16(v);
}

// ===========================================================================
// FALLBACK PATH (R1-verified, 231 us) — used only if ws is too small.
// ===========================================================================
template <typename T>
__device__ __forceinline__ void qproj_body_fb(const T* __restrict__ queries,
                                              const T* __restrict__ Wq,
                                              const T* __restrict__ bq,
                                              unsigned short* __restrict__ qws,
                                              unsigned short* Abuf, unsigned short* Bbuf) {
  const int Mt = blockIdx.x, Nt = blockIdx.y;
  const int tid = threadIdx.x;
  const int w = tid >> 6, l = tid & 63;
  const int quad = l >> 4, l16 = l & 15;
  const int wr = (w >> 1) * 64, wc = (w & 1) * 64;
  const int r_st = tid >> 1;
  const int kk_st = (tid & 1) * 16;
  const T* Asrc = queries + ((size_t)(Mt * 128 + r_st)) * 512 + kk_st;
  const T* Bsrc = Wq + ((size_t)(Nt * 128 + r_st)) * 512 + kk_st;

  const f32x4 zero4 = {0.f, 0.f, 0.f, 0.f};
  f32x4 acc[4][4];
#pragma unroll
  for (int i = 0; i < 4; ++i)
#pragma unroll
    for (int j = 0; j < 4; ++j) acc[i][j] = zero4;

  RegChunk<T> ra, rb;
  ra.load(Asrc);
  rb.load(Bsrc);
  for (int k0 = 0; k0 < 512; k0 += 32) {
    __syncthreads();
    ra.store(&Abuf[r_st * 32 + kk_st]);
    rb.store(&Bbuf[r_st * 32 + kk_st]);
    if (k0 + 32 < 512) {
      ra.load(Asrc + k0 + 32);
      rb.load(Bsrc + k0 + 32);
    }
    __syncthreads();
    s16x8 af[4], bfr[4];
#pragma unroll
    for (int i = 0; i < 4; ++i)
      af[i] = *reinterpret_cast<const s16x8*>(&Abuf[(wr + i * 16 + l16) * 32 + quad * 8]);
#pragma unroll
    for (int j = 0; j < 4; ++j)
      bfr[j] = *reinterpret_cast<const s16x8*>(&Bbuf[(wc + j * 16 + l16) * 32 + quad * 8]);
#pragma unroll
    for (int i = 0; i < 4; ++i)
#pragma unroll
      for (int j = 0; j < 4; ++j) acc[i][j] = mfma16(af[i], bfr[j], acc[i][j]);
  }
#pragma unroll
  for (int j = 0; j < 4; ++j) {
    float bb = tofl(bq[Nt * 128 + wc + j * 16 + l16]);
#pragma unroll
    for (int i = 0; i < 4; ++i)
#pragma unroll
      for (int rg = 0; rg < 4; ++rg) {
        int row = Mt * 128 + wr + i * 16 + quad * 4 + rg;
        int col = Nt * 128 + wc + j * 16 + l16;
        qws[(size_t)row * 512 + col] = f2bf(acc[i][j][rg] + bb);
      }
  }
}

__global__ __launch_bounds__(256) void k_qproj_fb(const void* queries, const void* Wq,
                                                  const void* bq, unsigned short* qws,
                                                  const unsigned short* __restrict__ det) {
  __shared__ unsigned short Abuf[128 * 32];
  __shared__ unsigned short Bbuf[128 * 32];
  if (detect_fp32(det))
    qproj_body_fb<float>((const float*)queries, (const float*)Wq, (const float*)bq, qws,
                         Abuf, Bbuf);
  else
    qproj_body_fb<__hip_bfloat16>((const __hip_bfloat16*)queries,
                                  (const __hip_bfloat16*)Wq, (const __hip_bfloat16*)bq, qws,
                                  Abuf, Bbuf);
}

template <typename T>
__device__ __forceinline__ void fused_body_fb(
    const T* __restrict__ inputs, const T* __restrict__ masks, const T* __restrict__ Wkv,
    const T* __restrict__ bkv, const unsigned short* __restrict__ qws,
    float* __restrict__ num, float* __restrict__ den, unsigned short* Abuf,
    unsigned short* Bbuf, unsigned short* kvbuf, unsigned short* vbuf,
    unsigned short* Pbuf) {
  const int stile = blockIdx.x;
  const int b = blockIdx.y;
  const int hp = blockIdx.z;
  const int s0 = stile * 128;
  const int tid = threadIdx.x;
  const int w = tid >> 6;
  const int l = tid & 63;
  const int quad = l >> 4;
  const int l16 = l & 15;
  const int which = w >> 2;
  const int wr = ((w >> 1) & 1) * 64;
  const int wc = (w & 1) * 64;

  const f32x4 zero4 = {0.f, 0.f, 0.f, 0.f};
  f32x4 acc[4][4];
#pragma unroll
  for (int i = 0; i < 4; ++i)
#pragma unroll
    for (int j = 0; j < 4; ++j) acc[i][j] = zero4;

  const int sr = tid >> 2;
  const int sc = tid & 3;
  const T* Asrc = inputs + ((size_t)(b * 4096 + s0 + sr)) * 512 + sc * 16;
  const T* BKs = Wkv + ((size_t)(hp * 128 + sr)) * 512 + sc * 16;
  const T* BVs = Wkv + ((size_t)(512 + hp * 128 + sr)) * 512 + sc * 16;
  unsigned short* ad0 = stg(Abuf, sr, sc * 2);
  unsigned short* ad1 = stg(Abuf, sr, sc * 2 + 1);
  unsigned short* bk0 = stg(Bbuf, sr, sc * 2);
  unsigned short* bk1 = stg(Bbuf, sr, sc * 2 + 1);
  unsigned short* bv0 = stg(Bbuf, 128 + sr, sc * 2);
  unsigned short* bv1 = stg(Bbuf, 128 + sr, sc * 2 + 1);

  RegChunk<T> ra0, ra1, rbk, rbv;
  ra0.load(Asrc);
  ra1.load(Asrc + 64);
  rbk.load(BKs);
  rbv.load(BVs);

#pragma unroll
  for (int it2 = 0; it2 < 4; ++it2) {
#pragma unroll
    for (int ph = 0; ph < 2; ++ph) {
      const int it = it2 * 2 + ph;
      RegChunk<T>& ra = ph ? ra1 : ra0;
      __syncthreads();
      ra.store2(ad0, ad1);
      rbk.store2(bk0, bk1);
      rbv.store2(bv0, bv1);
      if (it < 6) ra.load(Asrc + (it + 2) * 64);
      if (it < 7) {
        rbk.load(BKs + (it + 1) * 64);
        rbv.load(BVs + (it + 1) * 64);
      }
      __syncthreads();
#pragma unroll
      for (int kk2 = 0; kk2 < 2; ++kk2) {
        s16x8 af[4], bfr[4];
#pragma unroll
        for (int i = 0; i < 4; ++i)
          af[i] = *reinterpret_cast<const s16x8*>(stgc(Abuf, wr + i * 16 + l16, kk2 * 4 + quad));
#pragma unroll
        for (int j = 0; j < 4; ++j)
          bfr[j] = *reinterpret_cast<const s16x8*>(
              stgc(Bbuf, which * 128 + wc + j * 16 + l16, kk2 * 4 + quad));
#pragma unroll
        for (int i = 0; i < 4; ++i)
#pragma unroll
          for (int j = 0; j < 4; ++j) acc[i][j] = mfma16(af[i], bfr[j], acc[i][j]);
      }
    }
  }

#pragma unroll
  for (int j = 0; j < 4; ++j) {
    float bb = tofl(bkv[which * 512 + hp * 128 + wc + j * 16 + l16]);
#pragma unroll
    for (int i = 0; i < 4; ++i)
#pragma unroll
      for (int rg = 0; rg < 4; ++rg) {
        int sl = wr + i * 16 + quad * 4 + rg;
        int c = wc + j * 16 + l16;
        unsigned short bv = f2bf(acc[i][j][rg] + bb);
        if (which == 0)
          kvbuf[sw_idx(sl, c)] = bv;
        else
          vbuf[sw_idx(c, sl)] = bv;
      }
  }
  __syncthreads();

  const int hh = w >> 2, mt = (w >> 1) & 1, sh = w & 1;
  {
    f32x4 ua[4];
#pragma unroll
    for (int j = 0; j < 4; ++j) ua[j] = zero4;
#pragma unroll
    for (int kk = 0; kk < 2; ++kk) {
      s16x8 aq = *reinterpret_cast<const s16x8*>(
          qws + ((size_t)(b * 32 + mt * 16 + l16)) * 512 + hp * 128 + hh * 64 + kk * 32 +
          quad * 8);
#pragma unroll
      for (int j = 0; j < 4; ++j) {
        s16x8 bk = *reinterpret_cast<const s16x8*>(
            &kvbuf[sw_idx(sh * 64 + j * 16 + l16, hh * 64 + kk * 32 + quad * 8)]);
        ua[j] = mfma16(aq, bk, ua[j]);
      }
    }
    const float scale = 0.044194173824159216f;
    float dsum[4] = {0.f, 0.f, 0.f, 0.f};
#pragma unroll
    for (int j = 0; j < 4; ++j) {
      int scol = sh * 64 + j * 16 + l16;
      float mask = tofl(masks[(size_t)b * 4096 + s0 + scol]);
#pragma unroll
      for (int rg = 0; rg < 4; ++rg) {
        int qrow = mt * 16 + quad * 4 + rg;
        float uv = ua[j][rg] * scale;
        float e = uv > 0.f ? uv : (__expf(uv) - 1.f);
        e = fminf(e, 15.f);
        float p = __expf(e) * mask;
        unsigned short pu = f2bf(p);
        Pbuf[sw_idx(hh * 32 + qrow, scol)] = pu;
        dsum[rg] += bf2f(pu);
      }
    }
#pragma unroll
    for (int rg = 0; rg < 4; ++rg) {
      float s = dsum[rg];
      s += __shfl_xor(s, 1);
      s += __shfl_xor(s, 2);
      s += __shfl_xor(s, 4);
      s += __shfl_xor(s, 8);
      if (l16 == 0) {
        int qrow = mt * 16 + quad * 4 + rg;
        atomicAdd(&den[((size_t)(b * 32 + qrow)) * 8 + hp * 2 + hh], s);
      }
    }
  }
  __syncthreads();

  {
    const int dh = w & 1;
    f32x4 na[2];
    na[0] = zero4;
    na[1] = zero4;
#pragma unroll
    for (int kk = 0; kk < 4; ++kk) {
      s16x8 ap = *reinterpret_cast<const s16x8*>(
          &Pbuf[sw_idx(hh * 32 + mt * 16 + l16, kk * 32 + quad * 8)]);
#pragma unroll
      for (int jj = 0; jj < 2; ++jj) {
        int j = dh * 2 + jj;
        s16x8 bv = *reinterpret_cast<const s16x8*>(
            &vbuf[sw_idx(hh * 64 + j * 16 + l16, kk * 32 + quad * 8)]);
        na[jj] = mfma16(ap, bv, na[jj]);
      }
    }
    const int h = hp * 2 + hh;
#pragma unroll
    for (int jj = 0; jj < 2; ++jj) {
      int d = (dh * 2 + jj) * 16 + l16;
#pragma unroll
      for (int rg = 0; rg < 4; ++rg) {
        int qrow = mt * 16 + quad * 4 + rg;
        atomicAdd(&num[(((size_t)(b * 32 + qrow)) * 8 + h) * 64 + d], na[jj][rg]);
      }
    }
  }
}

__global__ __launch_bounds__(512, 2) void k_fused_fb(const void* inputs, const void* masks,
                                                     const void* Wkv, const void* bkv,
                                                     const unsigned short* __restrict__ qws,
                                                     float* __restrict__ num,
                                                     float* __restrict__ den) {
  __shared__ unsigned short Abuf[128 * 64];
  __shared__ unsigned short Bbuf[256 * 64];
  __shared__ unsigned short kvbuf[128 * 128];
  __shared__ unsigned short vbuf[128 * 128];
  __shared__ unsigned short Pbuf[64 * 128];
  if (detect_fp32((const unsigned short*)inputs))
    fused_body_fb<float>((const float*)inputs, (const float*)masks, (const float*)Wkv,
                         (const float*)bkv, qws, num, den, Abuf, Bbuf, kvbuf, vbuf, Pbuf);
  else
    fused_body_fb<__hip_bfloat16>((const __hip_bfloat16*)inputs,
                                  (const __hip_bfloat16*)masks, (const __hip_bfloat16*)Wkv,
                                  (const __hip_bfloat16*)bkv, qws, num, den, Abuf, Bbuf,
                                  kvbuf, vbuf, Pbuf);
}

__global__ __launch_bounds__(256) void k_div_fb(const float* __restrict__ num,
                                                const float* __restrict__ den, void* out,
                                                const unsigned short* __restrict__ det) {
  int i = blockIdx.x * 256 + threadIdx.x;
  float v = num[i] / den[i >> 6];
  if (detect_fp32(det))
    ((float*)out)[i] = v;
  else
    ((__hip_bfloat16*)out)[i] = __float2bfloat16(v);
}

// ---------------------------------------------------------------------------
extern "C" void kernel_launch(void* const* d_in, const int* in_sizes, int n_in,
                              void* d_out, int out_size, void* d_ws, size_t ws_size,
                              hipStream_t stream) {
  // d_in: 0 inputs, 1 queries, 2 masks, 3 Wkv, 4 bkv, 5 Wq, 6 bq
  char* ws = (char*)d_ws;
  if (ws_size >= 119802880) {
    // NEW path. ws (bytes):
    //   [0]         conv region (bf16, fp32 case only; 35,392,512 B)
    //   [102501376] qws bf16 [256][512]     (262,144 B)
    //   [102763520] num_part f32            (16,777,216 B)
    //   [119540736] den_part f32            (262,144 B)
    unsigned short* conv = (unsigned short*)ws;
    unsigned short* qws = (unsigned short*)(ws + 102501376);
    float* num_part = (float*)(ws + 102763520);
    float* den_part = (float*)(ws + 119540736);

    hipMemsetAsync(den_part, 0, 262144, stream);  // den accumulated via atomics
    k_conv<<<2120, 256, 0, stream>>>(d_in[0], d_in[1], d_in[3], d_in[5], d_in[4], d_in[6],
                                     conv);
    k_qp<<<8, 256, 0, stream>>>(conv, d_in[0], d_in[1], d_in[5], d_in[6], qws);
    k_fused2<<<1024, 512, 0, stream>>>(conv, d_in[0], d_in[2], d_in[3], d_in[4], qws,
                                       num_part, den_part);
    k_final<<<512, 256, 0, stream>>>(num_part, den_part, d_out,
                                     (const unsigned short*)d_in[0]);
  } else if (ws_size >= 802816) {
    // FALLBACK (R1 path). ws: [1024] den ; [16384] num ; [540672] qws
    float* den = (float*)(ws + 1024);
    float* num = (float*)(ws + 16384);
    unsigned short* qws = (unsigned short*)(ws + 540672);

    hipMemsetAsync(d_ws, 0, 540672, stream);
    dim3 gq(2, 4);
    k_qproj_fb<<<gq, 256, 0, stream>>>(d_in[1], d_in[5], d_in[6], qws,
                                       (const unsigned short*)d_in[0]);
    dim3 g2(32, 8, 4);
    k_fused_fb<<<g2, 512, 0, stream>>>(d_in[0], d_in[2], d_in[3], d_in[4], qws, num, den);
    k_div_fb<<<512, 256, 0, stream>>>(num, den, d_out, (const unsigned short*)d_in[0]);
  }
}